// Round 1
// 411.284 us; speedup vs baseline: 1.0759x; 1.0759x over previous
//
#include <hip/hip_runtime.h>
#include <math.h>

#define PI_F 3.14159265358979323846f
#define NPIX 262144   // 512*512

typedef __attribute__((ext_vector_type(8))) short sh8;
typedef __attribute__((ext_vector_type(4))) float fx4;
typedef __attribute__((ext_vector_type(4))) unsigned short ush4;

__device__ __forceinline__ unsigned short f2bf(float v) {
    unsigned u = __float_as_uint(v);
    return (unsigned short)((u + 0x7FFFu + ((u >> 16) & 1)) >> 16);
}
__device__ __forceinline__ float bf2f(unsigned short h) {
    return __uint_as_float((unsigned)h << 16);
}

// ---------------------------------------------------------------- dark channel
__global__ __launch_bounds__(256) void k_minc(const float* __restrict__ x, float* __restrict__ dm,
                                              int* __restrict__ gmax) {
    int p = blockIdx.x * 256 + threadIdx.x;
    if (p == 0) gmax[0] = 0;
    float m = fmaxf(x[p], fmaxf(x[p + NPIX], x[p + 2 * NPIX]));
    dm[p] = 1.0f - m;
}

__device__ __forceinline__ int refl512(int t) {
    if (t < 0) t = -t;
    if (t > 511) t = 1022 - t;
    return t;
}

__global__ __launch_bounds__(256) void k_minrow(const float* __restrict__ dm, float* __restrict__ tmp) {
    int p = blockIdx.x * 256 + threadIdx.x;
    int i = p >> 9, j = p & 511;
    float m = 1e30f;
    #pragma unroll
    for (int d = -7; d <= 7; d++) m = fminf(m, dm[(i << 9) + refl512(j + d)]);
    tmp[p] = m;
}

__global__ __launch_bounds__(256) void k_mincol_max(const float* __restrict__ tmp, float* __restrict__ dark,
                                                    int* __restrict__ gmax) {
    int p = blockIdx.x * 256 + threadIdx.x;
    int i = p >> 9, j = p & 511;
    float m = 1e30f;
    #pragma unroll
    for (int d = -7; d <= 7; d++) m = fminf(m, tmp[(refl512(i + d) << 9) + j]);
    dark[p] = m;
    __shared__ float red[256];
    int tid = threadIdx.x;
    red[tid] = m;
    __syncthreads();
    for (int s = 128; s > 0; s >>= 1) {
        if (tid < s) red[tid] = fmaxf(red[tid], red[tid + s]);
        __syncthreads();
    }
    if (tid == 0) atomicMax(gmax, __float_as_int(red[0]));
}

// ---------------------------------------------------------------- prep helpers (device)
__device__ __forceinline__ void prep_one(const float* __restrict__ w, unsigned short* __restrict__ h,
                                         unsigned short* __restrict__ l, int N, int K, int cshift, int idx) {
    if (idx >= N * K) return;
    int n = idx / K, kord = idx - n * K;
    int ksrc = kord;
    if (cshift) {
        int dydx = kord >> cshift, c = kord & ((1 << cshift) - 1);
        ksrc = c * 4 + dydx;
    }
    float v = w[n * K + ksrc];
    unsigned short hb = f2bf(v);
    h[idx] = hb;
    if (l) l[idx] = f2bf(v - bf2f(hb));
}

__device__ __forceinline__ void bfft_one(int idx,
                                         unsigned short* __restrict__ BfH, unsigned short* __restrict__ BfL,
                                         unsigned short* __restrict__ BfcH, unsigned short* __restrict__ BfcL,
                                         unsigned short* __restrict__ BicH, unsigned short* __restrict__ BicL,
                                         unsigned short* __restrict__ BirH, unsigned short* __restrict__ BirL,
                                         float* __restrict__ zbias) {
    if (idx < 256) zbias[idx] = 0.f;
    const float w0 = 2.f * PI_F / 128.f;
    float v;
    unsigned short *H, *L;
    int off;
    if (idx < 32768) {                     // Bf [256][128]
        int n = idx >> 7, k = idx & 127;
        int t = n & 127, r = (t * k) & 127;
        float s_, c_; sincosf(w0 * r, &s_, &c_);
        v = (n < 128) ? c_ : -s_;
        H = BfH; L = BfL; off = idx;
    } else if (idx < 98304) {              // Bfc [256][256]
        int i = idx - 32768;
        int n = i >> 8, j = i & 255;
        int t = n & 127, r = (t * (j & 127)) & 127;
        float s_, c_; sincosf(w0 * r, &s_, &c_);
        v = (n < 128) ? ((j < 128) ? c_ : s_) : ((j < 128) ? -s_ : c_);
        H = BfcH; L = BfcL; off = i;
    } else if (idx < 163840) {             // Bic [256][256]
        int i = idx - 98304;
        int n = i >> 8, j = i & 255;
        int t = n & 127, r = (t * (j & 127)) & 127;
        float s_, c_; sincosf(w0 * r, &s_, &c_);
        v = ((n < 128) ? ((j < 128) ? c_ : -s_) : ((j < 128) ? s_ : c_)) * (1.f / 128.f);
        H = BicH; L = BicL; off = i;
    } else if (idx < 184320) {             // Bir [128][160]
        int i = idx - 163840;
        int col = i / 160, j = i - col * 160;
        if (j == 0) v = 1.f / 128.f;
        else if (j < 64)  { int r = (j * col) & 127; float s_, c_; sincosf(w0 * r, &s_, &c_); v = 2.f * c_ / 128.f; }
        else if (j == 64) v = (col & 1) ? -1.f / 128.f : 1.f / 128.f;
        else if (j >= 66 && j <= 128) { int k = j - 65; int r = (k * col) & 127; float s_, c_; sincosf(w0 * r, &s_, &c_); v = -2.f * s_ / 128.f; }
        else v = 0.f;
        H = BirH; L = BirL; off = i;
    } else return;
    unsigned short hb = f2bf(v);
    H[off] = hb;
    L[off] = f2bf(v - bf2f(hb));
}

// ---------------------------------------------------------------- merged prep kernel
__global__ __launch_bounds__(256) void k_prep(
    const float* __restrict__ w_d1, unsigned short* __restrict__ d1h, unsigned short* __restrict__ d1l,
    const float* __restrict__ w_d2, unsigned short* __restrict__ d2h, unsigned short* __restrict__ d2l,
    const float* __restrict__ w_a1, unsigned short* __restrict__ a1h, unsigned short* __restrict__ a1l,
    const float* __restrict__ w_a2, unsigned short* __restrict__ a2h, unsigned short* __restrict__ a2l,
    const float* __restrict__ w_s1, unsigned short* __restrict__ s1h,
    const float* __restrict__ w_s2, unsigned short* __restrict__ s2h,
    const float* __restrict__ w_u3, const float* __restrict__ w_u4, unsigned short* __restrict__ u43h,
    const float* __restrict__ b_u3, const float* __restrict__ b_u4, float* __restrict__ b43,
    unsigned short* __restrict__ BfH, unsigned short* __restrict__ BfL,
    unsigned short* __restrict__ BfcH, unsigned short* __restrict__ BfcL,
    unsigned short* __restrict__ BicH, unsigned short* __restrict__ BicL,
    unsigned short* __restrict__ BirH, unsigned short* __restrict__ BirL,
    float* __restrict__ zbias,
    const float* __restrict__ w2, const float* __restrict__ b2,
    const float* __restrict__ w3, const float* __restrict__ b3,
    const float* __restrict__ wu2, const float* __restrict__ bu2,
    const float* __restrict__ wu1, const float* __restrict__ bu1,
    float* __restrict__ Wc, float* __restrict__ bc,
    float* __restrict__ W21c, float* __restrict__ b21c) {
    int b = blockIdx.x, tid = threadIdx.x;
    if (b < 128)       prep_one(w_d1, d1h, d1l, 128, 256, 6, b * 256 + tid);
    else if (b < 640)  prep_one(w_d2, d2h, d2l, 256, 512, 7, (b - 128) * 256 + tid);
    else if (b < 896)  prep_one(w_a1, a1h, a1l, 256, 256, 0, (b - 640) * 256 + tid);
    else if (b < 1152) prep_one(w_a2, a2h, a2l, 256, 256, 0, (b - 896) * 256 + tid);
    else if (b < 1408) prep_one(w_s1, s1h, nullptr, 256, 256, 0, (b - 1152) * 256 + tid);
    else if (b < 1664) prep_one(w_s2, s2h, nullptr, 256, 256, 0, (b - 1408) * 256 + tid);
    else if (b < 2384) bfft_one((b - 1664) * 256 + tid, BfH, BfL, BfcH, BfcL, BicH, BicL, BirH, BirL, zbias);
    else if (b < 2448) {
        int idx = (b - 2384) * 256 + tid;
        int n = idx >> 8, j = idx & 255;
        float s = 0.f;
        #pragma unroll 16
        for (int o = 0; o < 128; o++) s += w_u4[n * 128 + o] * w_u3[o * 256 + j];
        u43h[idx] = f2bf(s);
    } else {
        __shared__ float sWc[384], sW2c[384];
        if (tid < 128) {
            int j = tid;
            for (int r = 0; r < 3; r++) {
                float s = 0.f;
                #pragma unroll 16
                for (int o = 0; o < 64; o++) s += w3[r * 64 + o] * w2[o * 128 + j];
                sWc[r * 128 + j] = s;
                Wc[r * 128 + j] = s;
            }
            if (j < 3) {
                float s = b3[j];
                #pragma unroll 16
                for (int o = 0; o < 64; o++) s += w3[j * 64 + o] * b2[o];
                bc[j] = s;
            }
        }
        if (tid >= 128 && tid < 192) {
            int n = tid - 128;
            float s = b_u4[n];
            #pragma unroll 16
            for (int o = 0; o < 128; o++) s += w_u4[n * 128 + o] * b_u3[o];
            b43[n] = s;
        }
        __syncthreads();
        if (tid < 128) {
            int j = tid;
            for (int r = 0; r < 3; r++) {
                float s = 0.f;
                #pragma unroll 16
                for (int o = 0; o < 64; o++) s += sWc[r * 128 + o] * wu2[o * 128 + j];
                sW2c[r * 128 + j] = s;
            }
        }
        __syncthreads();
        if (tid < 256) {
            int j = tid;
            for (int r = 0; r < 3; r++) {
                float s = 0.f;
                #pragma unroll 16
                for (int o = 0; o < 128; o++) s += sW2c[r * 128 + o] * wu1[o * 256 + j];
                W21c[r * 256 + j] = s;
            }
        }
        if (tid < 3) {
            float s = 0.f;
            #pragma unroll 16
            for (int o = 0; o < 128; o++) s += sW2c[tid * 128 + o] * bu1[o];
            #pragma unroll 16
            for (int o = 0; o < 64; o++)  s += sWc[tid * 128 + o] * bu2[o];
            b21c[tid] = s;
        }
    }
}

// ---------------------------------------------------------------- x_f = e2(e1(x)), s2d [kord][m2] layout, bf16 out
__global__ __launch_bounds__(256) void k_ef2(const float* __restrict__ x,
                                             const float* __restrict__ w1, const float* __restrict__ b1,
                                             const float* __restrict__ w2, const float* __restrict__ b2,
                                             unsigned short* __restrict__ out) {
    __shared__ float sw1[24], sb1[8], sw2[512], sb2[64];
    int tid = threadIdx.x;
    if (tid < 24) sw1[tid] = w1[tid];
    if (tid < 8)  sb1[tid] = b1[tid];
    if (tid < 64) sb2[tid] = b2[tid];
    if (tid < 256) { sw2[tid] = w2[tid]; sw2[tid + 256] = w2[tid + 256]; }
    __syncthreads();
    int bid = blockIdx.x;
    int dydx = bid >> 8;
    int m2 = (bid & 255) * 256 + tid;
    int i = m2 >> 8, j = m2 & 255;
    int dy = dydx >> 1, dx = dydx & 1;
    int p5 = (2 * i + dy) * 512 + 2 * j + dx;
    float x0 = x[p5], x1 = x[p5 + NPIX], x2 = x[p5 + 2 * NPIX];
    float h[8];
    #pragma unroll
    for (int r = 0; r < 8; r++)
        h[r] = sw1[r * 3] * x0 + sw1[r * 3 + 1] * x1 + sw1[r * 3 + 2] * x2 + sb1[r];
    #pragma unroll 1
    for (int o = 0; o < 64; o++) {
        float acc = sb2[o];
        #pragma unroll
        for (int r = 0; r < 8; r++) acc += sw2[o * 8 + r] * h[r];
        out[(size_t)(dydx * 64 + o) * 65536 + m2] = f2bf(acc);
    }
}

// ---------------------------------------------------------------- channels-first MFMA GEMM
// C[n][m] (or TSTORE: C[m][n]) = sum_k B[n][k] * A(k, m) + bias[n]
// AMODE 0: A[k][m] [K][M] ; 1: s2d gather ; 3: A[m][K] ; 7: F2 read from F1T ; 8: I2 read from I1T
// ABF16: A source is pre-rounded bf16 (bit-identical to f2bf-on-load of fp32)
// CBF16: C stored as bf16 (bit-identical to f2bf-on-load by the consumer)
template<int AMODE, int SPLIT, int LRELU, int TSTORE, int ABF16, int CBF16>
__global__ __launch_bounds__(256) void k_mmcf(const void* __restrict__ Asrc_,
                                              const unsigned short* __restrict__ Bh,
                                              const unsigned short* __restrict__ Bl,
                                              const float* __restrict__ bias, void* __restrict__ C_,
                                              int M, int N, int K, int cshift, int wshift, int srcW) {
    const float* Af = (const float*)Asrc_;
    const unsigned short* A16 = (const unsigned short*)Asrc_;
    float* Cf = (float*)C_;
    unsigned short* C16 = (unsigned short*)C_;
    __shared__ unsigned short AhS[128 * 40];
    __shared__ unsigned short BhS[64 * 40];
    __shared__ unsigned short AlS[SPLIT ? 128 * 40 : 8];
    __shared__ unsigned short BlS[SPLIT ? 64 * 40 : 8];
    int tid = threadIdx.x;
    int m0 = blockIdx.x * 128;
    int n0 = blockIdx.y * 64;
    int wave = tid >> 6, lane = tid & 63;
    int wm = (wave >> 1) * 64, wn = (wave & 1) * 32;
    int l15 = lane & 15, quad = lane >> 4;
    int lk = quad * 8, lk4 = quad * 4;
    fx4 acc[4][2];
    #pragma unroll
    for (int a = 0; a < 4; a++)
        #pragma unroll
        for (int b = 0; b < 2; b++)
            acc[a][b] = (fx4){0.f, 0.f, 0.f, 0.f};

    int mm = tid & 127;
    int kpb = tid >> 7;
    int gm = m0 + mm;
    int oj = 0, oi = 0, cA = 0, kfA = 0, tauA = 0;
    size_t abase = 0;
    if (AMODE == 1) { oj = gm & ((1 << wshift) - 1); oi = gm >> wshift; }
    if (AMODE == 3) abase = (size_t)gm * K;
    if (AMODE == 7) { cA = gm / 65; kfA = gm - cA * 65; }
    if (AMODE == 8) { cA = gm >> 7; tauA = gm & 127; }

    for (int kb = 0; kb < K; kb += 32) {
        #pragma unroll
        for (int half = 0; half < 2; half++) {
            sh8 hv, lv;
            #pragma unroll
            for (int tt = 0; tt < 4; tt++) {
                int kp = kpb * 8 + half * 4 + tt;
                int k0 = kb + kp * 2;
                size_t ad0, ad1;
                if (AMODE == 0) {
                    ad0 = (size_t)k0 * M + gm;
                    ad1 = ad0 + M;
                } else if (AMODE == 1) {
                    int c = k0 & ((1 << cshift) - 1);
                    int dydx = k0 >> cshift;
                    int dy = dydx >> 1, dx = dydx & 1;
                    size_t pix = (size_t)(2 * oi + dy) * srcW + (2 * oj + dx);
                    size_t plane = (size_t)srcW * srcW;
                    ad0 = (size_t)c * plane + pix;
                    ad1 = ad0 + plane;
                } else if (AMODE == 3) {
                    ad0 = abase + k0;
                    ad1 = ad0 + 1;
                } else if (AMODE == 7) {
                    int t0 = k0 & 127, hf = k0 >> 7;
                    ad0 = (size_t)(cA * 128 + t0) * 256 + hf * 128 + kfA;
                    ad1 = ad0 + 256;
                } else {                       // AMODE 8
                    int j0 = k0, j1 = k0 + 1;
                    int kf0 = (j0 < 65) ? j0 : ((j0 < 130) ? j0 - 65 : 0);
                    int hf0 = (j0 >= 65 && j0 < 130) ? 1 : 0;
                    int kf1 = (j1 < 65) ? j1 : ((j1 < 130) ? j1 - 65 : 0);
                    int hf1 = (j1 >= 65 && j1 < 130) ? 1 : 0;
                    ad0 = (size_t)(cA * 65 + kf0) * 256 + hf0 * 128 + tauA;
                    ad1 = (size_t)(cA * 65 + kf1) * 256 + hf1 * 128 + tauA;
                }
                unsigned short h0, h1;
                if (ABF16) {
                    h0 = A16[ad0];
                    h1 = A16[ad1];
                } else {
                    float a0 = Af[ad0], a1 = Af[ad1];
                    h0 = f2bf(a0);
                    h1 = f2bf(a1);
                    if (SPLIT) {
                        lv[tt * 2] = (short)f2bf(a0 - bf2f(h0));
                        lv[tt * 2 + 1] = (short)f2bf(a1 - bf2f(h1));
                    }
                }
                hv[tt * 2] = (short)h0;
                hv[tt * 2 + 1] = (short)h1;
            }
            int coff = (kpb * 2 + half) * 8;
            *(sh8*)(void*)&AhS[mm * 40 + coff] = hv;
            if (SPLIT) *(sh8*)(void*)&AlS[mm * 40 + coff] = lv;
        }
        {
            int n = tid >> 2, seg = tid & 3;
            size_t gb = (size_t)(n0 + n) * K + kb + seg * 8;
            *(sh8*)(void*)&BhS[n * 40 + seg * 8] = *(const sh8*)(const void*)&Bh[gb];
            if (SPLIT) *(sh8*)(void*)&BlS[n * 40 + seg * 8] = *(const sh8*)(const void*)&Bl[gb];
        }
        __syncthreads();
        sh8 af[4], bf[2], afl[4], bfl[2];
        #pragma unroll
        for (int mt = 0; mt < 4; mt++) {
            af[mt] = *(const sh8*)(const void*)&AhS[(wm + mt * 16 + l15) * 40 + lk];
            if (SPLIT) afl[mt] = *(const sh8*)(const void*)&AlS[(wm + mt * 16 + l15) * 40 + lk];
        }
        #pragma unroll
        for (int nt = 0; nt < 2; nt++) {
            bf[nt] = *(const sh8*)(const void*)&BhS[(wn + nt * 16 + l15) * 40 + lk];
            if (SPLIT) bfl[nt] = *(const sh8*)(const void*)&BlS[(wn + nt * 16 + l15) * 40 + lk];
        }
        #pragma unroll
        for (int mt = 0; mt < 4; mt++)
            #pragma unroll
            for (int nt = 0; nt < 2; nt++) {
                acc[mt][nt] = __builtin_amdgcn_mfma_f32_16x16x32_bf16(af[mt], bf[nt], acc[mt][nt], 0, 0, 0);
                if (SPLIT) {
                    acc[mt][nt] = __builtin_amdgcn_mfma_f32_16x16x32_bf16(af[mt], bfl[nt], acc[mt][nt], 0, 0, 0);
                    acc[mt][nt] = __builtin_amdgcn_mfma_f32_16x16x32_bf16(afl[mt], bf[nt], acc[mt][nt], 0, 0, 0);
                }
            }
        __syncthreads();
    }
    #pragma unroll
    for (int nt = 0; nt < 2; nt++) {
        int n = n0 + wn + nt * 16 + l15;
        float bs = bias[n];
        #pragma unroll
        for (int mt = 0; mt < 4; mt++) {
            int mbase = m0 + wm + mt * 16 + lk4;
            if (TSTORE) {
                #pragma unroll
                for (int r = 0; r < 4; r++) {
                    float q = acc[mt][nt][r] + bs;
                    if (LRELU) q = (q < 0.f) ? 0.1f * q : q;
                    if (CBF16) C16[(size_t)(mbase + r) * N + n] = f2bf(q);
                    else       Cf[(size_t)(mbase + r) * N + n] = q;
                }
            } else if (CBF16) {
                ush4 v;
                #pragma unroll
                for (int r = 0; r < 4; r++) {
                    float q = acc[mt][nt][r] + bs;
                    if (LRELU) q = (q < 0.f) ? 0.1f * q : q;
                    v[r] = f2bf(q);
                }
                *(ush4*)(void*)&C16[(size_t)n * M + mbase] = v;
            } else {
                float4 v;
                float* vp = (float*)&v;
                #pragma unroll
                for (int r = 0; r < 4; r++) {
                    float q = acc[mt][nt][r] + bs;
                    if (LRELU) q = (q < 0.f) ? 0.1f * q : q;
                    vp[r] = q;
                }
                *(float4*)&Cf[(size_t)n * M + mbase] = v;
            }
        }
    }
}

// ---------------------------------------------------------------- amp = sqrt(re^2+im^2), layout -> [c][t][kf]
__global__ __launch_bounds__(128) void k_ampc(const float* __restrict__ F2C, float* __restrict__ ampb) {
    int bid = blockIdx.x;
    int kf = threadIdx.x;
    if (kf >= 65) return;
    int c = bid >> 7, t = bid & 127;
    size_t m = (size_t)c * 65 + kf;
    float re = F2C[(size_t)t * 16640 + m];
    float im = F2C[(size_t)(t + 128) * 16640 + m];
    ampb[(size_t)bid * 65 + kf] = sqrtf(re * re + im * im);
}

// ---------------------------------------------------------------- z = a*(cos a, sin a) -> stacked [t][(c,kf)] planes, bf16
__global__ __launch_bounds__(128) void k_zbuild(const float* __restrict__ A2, unsigned short* __restrict__ Z) {
    int bid = blockIdx.x;
    int kf = threadIdx.x;
    if (kf >= 65) return;
    int c = bid >> 7, t = bid & 127;
    float a = A2[(size_t)bid * 65 + kf];
    float s_, c_;
    sincosf(a, &s_, &c_);
    size_t m = (size_t)c * 65 + kf;
    Z[(size_t)t * 16640 + m] = f2bf(a * c_);
    Z[2129920 + (size_t)t * 16640 + m] = f2bf(a * s_);
}

// ---------------------------------------------------------------- h3s = W21c @ I2T + b21c  (3ch @128^2, K=256)
__global__ __launch_bounds__(256) void k_h3s(const float* __restrict__ I2T, const float* __restrict__ W21c,
                                             const float* __restrict__ b21c, float* __restrict__ h3s) {
    __shared__ float wa[768], bs[3];
    int tid = threadIdx.x;
    for (int i = tid; i < 768; i += 256) wa[i] = W21c[i];
    if (tid < 3) bs[tid] = b21c[tid];
    __syncthreads();
    int q = blockIdx.x * 256 + tid;
    float a0 = bs[0], a1 = bs[1], a2 = bs[2];
    #pragma unroll 4
    for (int c = 0; c < 256; c++) {
        float v = I2T[(size_t)c * 16384 + q];
        a0 += wa[c] * v;
        a1 += wa[256 + c] * v;
        a2 += wa[512 + c] * v;
    }
    h3s[q] = a0; h3s[16384 + q] = a1; h3s[32768 + q] = a2;
}

// ---------------------------------------------------------------- channels-first bilinear x2 resize
__global__ __launch_bounds__(256) void k_resize2(const float* __restrict__ src, float* __restrict__ dst,
                                                 int C, int H) {
    int W2 = 2 * H;
    size_t idx = (size_t)blockIdx.x * 256 + threadIdx.x;
    size_t plane = (size_t)W2 * W2;
    if (idx >= (size_t)C * plane) return;
    int c = (int)(idx / plane);
    int rem = (int)(idx - (size_t)c * plane);
    int i = rem / W2, j = rem - i * W2;
    int ky = i >> 1, ylo, yhi; float wyl, wyh;
    if ((i & 1) == 0) { ylo = ky - 1; yhi = ky; wyl = .25f; wyh = .75f; if (ylo < 0) { ylo = 0; wyl = 0.f; wyh = 1.f; } }
    else              { ylo = ky; yhi = ky + 1; wyl = .75f; wyh = .25f; if (yhi > H - 1) { yhi = H - 1; wyh = 0.f; wyl = 1.f; } }
    int kx = j >> 1, xlo, xhi; float wxl, wxh;
    if ((j & 1) == 0) { xlo = kx - 1; xhi = kx; wxl = .25f; wxh = .75f; if (xlo < 0) { xlo = 0; wxl = 0.f; wxh = 1.f; } }
    else              { xlo = kx; xhi = kx + 1; wxl = .75f; wxh = .25f; if (xhi > H - 1) { xhi = H - 1; wxh = 0.f; wxl = 1.f; } }
    const float* p = src + (size_t)c * H * H;
    dst[idx] = wyl * (wxl * p[(size_t)ylo * H + xlo] + wxh * p[(size_t)ylo * H + xhi]) +
               wyh * (wxl * p[(size_t)yhi * H + xlo] + wxh * p[(size_t)yhi * H + xhi]);
}

// ---------------------------------------------------------------- final fused stage @512^2
__global__ __launch_bounds__(256) void k_final(const float* __restrict__ x,
                                               const float* __restrict__ dark, const int* __restrict__ gmax,
                                               const float* __restrict__ wcf1, const float* __restrict__ bcf1,
                                               const float* __restrict__ Wc, const float* __restrict__ bc,
                                               const float* __restrict__ g4, const float* __restrict__ h3,
                                               float* __restrict__ out) {
    __shared__ float dimt[32], w1[192], b1[64], wb[192], bcs[3];
    int tid = threadIdx.x;
    if (tid < 32) dimt[tid] = powf(10000.f, (float)(2 * (tid >> 1)) / 32.f);
    if (tid < 192) w1[tid] = wcf1[tid];
    if (tid < 64) b1[tid] = bcf1[tid];
    if (tid < 192) { int r = tid / 64, c = tid - (tid / 64) * 64; wb[tid] = Wc[r * 128 + 64 + c]; }
    if (tid < 3) bcs[tid] = bc[tid];
    __syncthreads();
    int p = blockIdx.x * 256 + threadIdx.x;
    int i = p >> 9, j = p & 511;
    const float scale = 2.f * PI_F;
    float inv511 = scale / (511.f + 1e-6f);
    float xe = (float)j * inv511, ye = (float)i * inv511;
    float gm = __int_as_float(gmax[0]);
    float ze = dark[p] / (gm + 1e-6f) * scale;
    float x0 = x[p], x1 = x[p + NPIX], x2 = x[p + 2 * NPIX];

    int ky = i >> 1, ylo, yhi; float wyl, wyh;
    if ((i & 1) == 0) { ylo = ky - 1; yhi = ky; wyl = .25f; wyh = .75f; if (ylo < 0) { ylo = 0; wyl = 0.f; wyh = 1.f; } }
    else              { ylo = ky; yhi = ky + 1; wyl = .75f; wyh = .25f; if (yhi > 255) { yhi = 255; wyh = 0.f; wyl = 1.f; } }
    int kx = j >> 1, xlo, xhi; float wxl, wxh;
    if ((j & 1) == 0) { xlo = kx - 1; xhi = kx; wxl = .25f; wxh = .75f; if (xlo < 0) { xlo = 0; wxl = 0.f; wxh = 1.f; } }
    else              { xlo = kx; xhi = kx + 1; wxl = .75f; wxh = .25f; if (xhi > 255) { xhi = 255; wxh = 0.f; wxl = 1.f; } }
    int s00 = ylo * 256 + xlo, s01 = ylo * 256 + xhi, s10 = yhi * 256 + xlo, s11 = yhi * 256 + xhi;
    float w00 = wyl * wxl, w01 = wyl * wxh, w10 = wyh * wxl, w11 = wyh * wxh;

    float a0 = 0.f, a1 = 0.f, a2 = 0.f;
    #pragma unroll 1
    for (int c = 0; c < 64; c++) {
        float e = (c < 16) ? xe / dimt[c] : (c < 32) ? ye / dimt[c - 16] : ze / dimt[c - 32];
        float sn, cs;
        __sincosf(e, &sn, &cs);
        float pos = ((c & 1) == 0) ? sn : cs;
        float ape = pos + w1[c * 3] * x0 + w1[c * 3 + 1] * x1 + w1[c * 3 + 2] * x2 + b1[c];
        const float* gp = g4 + (size_t)c * 65536;
        float gv = w00 * gp[s00] + w01 * gp[s01] + w10 * gp[s10] + w11 * gp[s11];
        float s = gv * ape;
        a0 += wb[c] * s; a1 += wb[64 + c] * s; a2 += wb[128 + c] * s;
    }
    float f0 = w00 * h3[s00] + w01 * h3[s01] + w10 * h3[s10] + w11 * h3[s11];
    const float* h1 = h3 + 65536;
    float f1 = w00 * h1[s00] + w01 * h1[s01] + w10 * h1[s10] + w11 * h1[s11];
    const float* h2 = h3 + 131072;
    float f2 = w00 * h2[s00] + w01 * h2[s01] + w10 * h2[s10] + w11 * h2[s11];
    out[p]            = a0 + f0 + bcs[0] + x0;
    out[NPIX + p]     = a1 + f1 + bcs[1] + x1;
    out[2 * NPIX + p] = a2 + f2 + bcs[2] + x2;
}

// ================================================================ launcher
extern "C" void kernel_launch(void* const* d_in, const int* in_sizes, int n_in,
                              void* d_out, int out_size, void* d_ws, size_t ws_size,
                              hipStream_t stream) {
    const float* x      = (const float*)d_in[0];
    const float* w_cf1  = (const float*)d_in[1];  const float* b_cf1 = (const float*)d_in[2];
    const float* w_e1   = (const float*)d_in[3];  const float* b_e1  = (const float*)d_in[4];
    const float* w_e2   = (const float*)d_in[5];  const float* b_e2  = (const float*)d_in[6];
    const float* w_d1   = (const float*)d_in[7];  const float* b_d1  = (const float*)d_in[8];
    const float* w_d2   = (const float*)d_in[9];  const float* b_d2  = (const float*)d_in[10];
    // 11..14: pha branch is dead code in the reference
    const float* w_amp1 = (const float*)d_in[15]; const float* b_amp1 = (const float*)d_in[16];
    const float* w_amp2 = (const float*)d_in[17]; const float* b_amp2 = (const float*)d_in[18];
    const float* w_sp1  = (const float*)d_in[19]; const float* b_sp1  = (const float*)d_in[20];
    const float* w_sp2  = (const float*)d_in[21]; const float* b_sp2  = (const float*)d_in[22];
    const float* w_u1   = (const float*)d_in[23]; const float* b_u1   = (const float*)d_in[24];
    const float* w_u2   = (const float*)d_in[25]; const float* b_u2   = (const float*)d_in[26];
    const float* w_u3   = (const float*)d_in[27]; const float* b_u3   = (const float*)d_in[28];
    const float* w_u4   = (const float*)d_in[29]; const float* b_u4   = (const float*)d_in[30];
    const float* w_cf2  = (const float*)d_in[31]; const float* b_cf2  = (const float*)d_in[32];
    const float* w_cf3  = (const float*)d_in[33]; const float* b_cf3  = (const float*)d_in[34];
    float* out = (float*)d_out;

    char* ws = (char*)d_ws;
    constexpr size_t MiB = 1ull << 20;
    float*  dark   = (float*)(ws + 0 * MiB);
    float*  tmp    = (float*)(ws + 1 * MiB);
    int*    gmax   = (int*)  (ws + 2 * MiB);
    float*  Wc     = (float*)(ws + 2 * MiB + 1024);
    float*  bc     = (float*)(ws + 2 * MiB + 2560);
    float*  W21c   = (float*)(ws + 2 * MiB + 4096);
    float*  b21c   = (float*)(ws + 2 * MiB + 7168);
    float*  b43    = (float*)(ws + 2 * MiB + 7424);
    unsigned short* xfs = (unsigned short*)(ws + 3 * MiB);    // bf16 [256][65536] = 32 MiB
    unsigned short* xd1 = (unsigned short*)(ws + 67 * MiB);   // bf16 [128][65536] = 16 MiB
    unsigned short* xd2 = (unsigned short*)(ws + 99 * MiB);   // bf16 [256][16384] =  8 MiB
    unsigned short* F1T = (unsigned short*)(ws + 115 * MiB);  // bf16 [32768][256] = 16 MiB
    float*  F2C    = (float*)(ws + 147 * MiB);                // fp32 (feeds sqrt)
    float*  ampb   = (float*)(ws + 164 * MiB);                // fp32 (split MLP)
    float*  A1     = (float*)(ws + 173 * MiB);
    float*  A2     = (float*)(ws + 182 * MiB);
    unsigned short* Zbuf = (unsigned short*)(ws + 115 * MiB); // bf16 [256][16640] x... (F1T dead after F2)
    unsigned short* I1T  = (unsigned short*)(ws + 132 * MiB); // bf16 [16640][256] = 8.5 MiB
    float*  I2T    = (float*)(ws + 149 * MiB);                // fp32 (feeds h3s fp32 dot)
    float*  h3s    = (float*)(ws + 11 * MiB);
    float*  h3     = (float*)(ws + 27 * MiB);
    unsigned short* s1 = (unsigned short*)(ws + 31 * MiB);    // bf16 [256][16384] = 8 MiB
    unsigned short* s2 = (unsigned short*)(ws + 47 * MiB);    // bf16
    float*  g4out  = (float*)(ws + 71 * MiB);
    float*  g4s    = (float*)(ws + 87 * MiB);
    unsigned short* wb16 = (unsigned short*)(ws + 192 * MiB);
    unsigned short* d1h = wb16 + 0,       * d1l = wb16 + 32768;
    unsigned short* d2h = wb16 + 65536,   * d2l = wb16 + 196608;
    unsigned short* a1h = wb16 + 327680,  * a1l = wb16 + 393216;
    unsigned short* a2h = wb16 + 458752,  * a2l = wb16 + 524288;
    unsigned short* s1h = wb16 + 589824;
    unsigned short* s2h = wb16 + 655360;
    unsigned short* u43h = wb16 + 720896;
    unsigned short* BfH = wb16 + 786432,  * BfL = wb16 + 819200;
    unsigned short* BfcH = wb16 + 851968, * BfcL = wb16 + 917504;
    unsigned short* BicH = wb16 + 983040, * BicL = wb16 + 1048576;
    unsigned short* BirH = wb16 + 1114112,* BirL = wb16 + 1134592;
    float* zbias = (float*)(ws + 195 * MiB + 512 * 1024);

    // 1) dark channel + gmax ; merged prep
    k_minc<<<1024, 256, 0, stream>>>(x, dark, gmax);
    k_minrow<<<1024, 256, 0, stream>>>(dark, tmp);
    k_mincol_max<<<1024, 256, 0, stream>>>(tmp, dark, gmax);
    k_prep<<<2449, 256, 0, stream>>>(
        w_d1, d1h, d1l, w_d2, d2h, d2l, w_amp1, a1h, a1l, w_amp2, a2h, a2l,
        w_sp1, s1h, w_sp2, s2h,
        w_u3, w_u4, u43h, b_u3, b_u4, b43,
        BfH, BfL, BfcH, BfcL, BicH, BicL, BirH, BirL, zbias,
        w_cf2, b_cf2, w_cf3, b_cf3, w_u2, b_u2, w_u1, b_u1, Wc, bc, W21c, b21c);

    // 2) e1/e2 in s2d layout (bf16 out) ; d1 ; d2 — all-bf16 intermediate chain
    k_ef2<<<1024, 256, 0, stream>>>(x, w_e1, b_e1, w_e2, b_e2, xfs);
    k_mmcf<0, 0, 0, 0, 1, 1><<<dim3(512, 2), 256, 0, stream>>>(xfs, d1h, nullptr, b_d1, xd1, 65536, 128, 256, 0, 0, 0);
    k_mmcf<1, 0, 0, 0, 1, 1><<<dim3(128, 4), 256, 0, stream>>>(xd1, d2h, nullptr, b_d2, xd2, 16384, 256, 512, 7, 7, 256);

    // 3) FFT section (bf16 DFT GEMMs; amp MLP stays fp32 split-bf16 for phase safety)
    k_mmcf<3, 0, 0, 1, 1, 1><<<dim3(256, 4), 256, 0, stream>>>(xd2, BfH, nullptr, zbias, F1T, 32768, 256, 128, 0, 0, 0);
    k_mmcf<7, 0, 0, 0, 1, 0><<<dim3(130, 4), 256, 0, stream>>>(F1T, BfcH, nullptr, zbias, F2C, 16640, 256, 256, 0, 0, 0);
    k_ampc<<<32768, 128, 0, stream>>>(F2C, ampb);
    k_mmcf<0, 1, 1, 0, 0, 0><<<dim3(65, 4), 256, 0, stream>>>(ampb, a1h, a1l, b_amp1, A1, 8320, 256, 256, 0, 0, 0);
    k_mmcf<0, 1, 0, 0, 0, 0><<<dim3(65, 4), 256, 0, stream>>>(A1, a2h, a2l, b_amp2, A2, 8320, 256, 256, 0, 0, 0);
    k_zbuild<<<32768, 128, 0, stream>>>(A2, Zbuf);
    k_mmcf<0, 0, 0, 1, 1, 1><<<dim3(130, 4), 256, 0, stream>>>(Zbuf, BicH, nullptr, zbias, I1T, 16640, 256, 256, 0, 0, 0);
    k_mmcf<8, 0, 0, 1, 1, 0><<<dim3(256, 2), 256, 0, stream>>>(I1T, BirH, nullptr, zbias, I2T, 32768, 128, 160, 0, 0, 0);

    // 4) four path: h3s = W21c @ I2T ; resize 3ch
    k_h3s<<<64, 256, 0, stream>>>(I2T, W21c, b21c, h3s);
    k_resize2<<<768, 256, 0, stream>>>(h3s, h3, 3, 128);

    // 5) spat path: sp1, sp2, composed u43 GEMM ; resize 64ch
    k_mmcf<0, 0, 1, 0, 1, 1><<<dim3(128, 4), 256, 0, stream>>>(xd2, s1h, nullptr, b_sp1, s1, 16384, 256, 256, 0, 0, 0);
    k_mmcf<0, 0, 0, 0, 1, 1><<<dim3(128, 4), 256, 0, stream>>>(s1, s2h, nullptr, b_sp2, s2, 16384, 256, 256, 0, 0, 0);
    k_mmcf<0, 0, 0, 0, 1, 0><<<dim3(128, 1), 256, 0, stream>>>(s2, u43h, nullptr, b43, g4s, 16384, 64, 256, 0, 0, 0);
    k_resize2<<<16384, 256, 0, stream>>>(g4s, g4out, 64, 128);

    // 6) final fused stage
    k_final<<<1024, 256, 0, stream>>>(x, dark, gmax, w_cf1, b_cf1, Wc, bc, g4out, h3, out);
}

// Round 2
// 399.745 us; speedup vs baseline: 1.1070x; 1.0289x over previous
//
#include <hip/hip_runtime.h>
#include <math.h>

#define PI_F 3.14159265358979323846f
#define NPIX 262144   // 512*512

typedef __attribute__((ext_vector_type(8))) short sh8;
typedef __attribute__((ext_vector_type(4))) float fx4;
typedef __attribute__((ext_vector_type(4))) unsigned short ush4;

__device__ __forceinline__ unsigned short f2bf(float v) {
    unsigned u = __float_as_uint(v);
    return (unsigned short)((u + 0x7FFFu + ((u >> 16) & 1)) >> 16);
}
__device__ __forceinline__ float bf2f(unsigned short h) {
    return __uint_as_float((unsigned)h << 16);
}

__device__ __forceinline__ int refl512(int t) {
    if (t < 0) t = -t;
    if (t > 511) t = 1022 - t;
    return t;
}

// ---------------------------------------------------------------- dark channel (fused min-c + row-min)
__global__ __launch_bounds__(256) void k_mrow(const float* __restrict__ x, float* __restrict__ tmp,
                                              int* __restrict__ gmax) {
    __shared__ float row[512];
    int i = blockIdx.x, tid = threadIdx.x;
    if (i == 0 && tid == 0) gmax[0] = 0;
    #pragma unroll
    for (int h = 0; h < 2; h++) {
        int j = tid + h * 256;
        int p = (i << 9) + j;
        float m = fmaxf(x[p], fmaxf(x[p + NPIX], x[p + 2 * NPIX]));
        row[j] = 1.0f - m;
    }
    __syncthreads();
    #pragma unroll
    for (int h = 0; h < 2; h++) {
        int j = tid + h * 256;
        float m = 1e30f;
        #pragma unroll
        for (int d = -7; d <= 7; d++) m = fminf(m, row[refl512(j + d)]);
        tmp[(i << 9) + j] = m;
    }
}

__global__ __launch_bounds__(256) void k_mincol_max(const float* __restrict__ tmp, float* __restrict__ dark,
                                                    int* __restrict__ gmax) {
    int p = blockIdx.x * 256 + threadIdx.x;
    int i = p >> 9, j = p & 511;
    float m = 1e30f;
    #pragma unroll
    for (int d = -7; d <= 7; d++) m = fminf(m, tmp[(refl512(i + d) << 9) + j]);
    dark[p] = m;
    __shared__ float red[256];
    int tid = threadIdx.x;
    red[tid] = m;
    __syncthreads();
    for (int s = 128; s > 0; s >>= 1) {
        if (tid < s) red[tid] = fmaxf(red[tid], red[tid + s]);
        __syncthreads();
    }
    if (tid == 0) atomicMax(gmax, __float_as_int(red[0]));
}

// ---------------------------------------------------------------- prep helpers (device)
__device__ __forceinline__ void prep_one(const float* __restrict__ w, unsigned short* __restrict__ h,
                                         unsigned short* __restrict__ l, int N, int K, int cshift, int idx) {
    if (idx >= N * K) return;
    int n = idx / K, kord = idx - n * K;
    int ksrc = kord;
    if (cshift) {
        int dydx = kord >> cshift, c = kord & ((1 << cshift) - 1);
        ksrc = c * 4 + dydx;
    }
    float v = w[n * K + ksrc];
    unsigned short hb = f2bf(v);
    h[idx] = hb;
    if (l) l[idx] = f2bf(v - bf2f(hb));
}

__device__ __forceinline__ void bfft_one(int idx,
                                         unsigned short* __restrict__ BfH, unsigned short* __restrict__ BfL,
                                         unsigned short* __restrict__ BfcH, unsigned short* __restrict__ BfcL,
                                         unsigned short* __restrict__ BicH, unsigned short* __restrict__ BicL,
                                         unsigned short* __restrict__ BirH, unsigned short* __restrict__ BirL,
                                         float* __restrict__ zbias) {
    if (idx < 256) zbias[idx] = 0.f;
    const float w0 = 2.f * PI_F / 128.f;
    float v;
    unsigned short *H, *L;
    int off;
    if (idx < 32768) {                     // Bf [256][128]
        int n = idx >> 7, k = idx & 127;
        int t = n & 127, r = (t * k) & 127;
        float s_, c_; sincosf(w0 * r, &s_, &c_);
        v = (n < 128) ? c_ : -s_;
        H = BfH; L = BfL; off = idx;
    } else if (idx < 98304) {              // Bfc [256][256]
        int i = idx - 32768;
        int n = i >> 8, j = i & 255;
        int t = n & 127, r = (t * (j & 127)) & 127;
        float s_, c_; sincosf(w0 * r, &s_, &c_);
        v = (n < 128) ? ((j < 128) ? c_ : s_) : ((j < 128) ? -s_ : c_);
        H = BfcH; L = BfcL; off = i;
    } else if (idx < 163840) {             // Bic [256][256]
        int i = idx - 98304;
        int n = i >> 8, j = i & 255;
        int t = n & 127, r = (t * (j & 127)) & 127;
        float s_, c_; sincosf(w0 * r, &s_, &c_);
        v = ((n < 128) ? ((j < 128) ? c_ : -s_) : ((j < 128) ? s_ : c_)) * (1.f / 128.f);
        H = BicH; L = BicL; off = i;
    } else if (idx < 184320) {             // Bir [128][160]
        int i = idx - 163840;
        int col = i / 160, j = i - col * 160;
        if (j == 0) v = 1.f / 128.f;
        else if (j < 64)  { int r = (j * col) & 127; float s_, c_; sincosf(w0 * r, &s_, &c_); v = 2.f * c_ / 128.f; }
        else if (j == 64) v = (col & 1) ? -1.f / 128.f : 1.f / 128.f;
        else if (j >= 66 && j <= 128) { int k = j - 65; int r = (k * col) & 127; float s_, c_; sincosf(w0 * r, &s_, &c_); v = -2.f * s_ / 128.f; }
        else v = 0.f;
        H = BirH; L = BirL; off = i;
    } else return;
    unsigned short hb = f2bf(v);
    H[off] = hb;
    L[off] = f2bf(v - bf2f(hb));
}

// ---------------------------------------------------------------- merged prep kernel
__global__ __launch_bounds__(256) void k_prep(
    const float* __restrict__ w_d1, unsigned short* __restrict__ d1h, unsigned short* __restrict__ d1l,
    const float* __restrict__ w_d2, unsigned short* __restrict__ d2h, unsigned short* __restrict__ d2l,
    const float* __restrict__ w_a1, unsigned short* __restrict__ a1h, unsigned short* __restrict__ a1l,
    const float* __restrict__ w_a2, unsigned short* __restrict__ a2h, unsigned short* __restrict__ a2l,
    const float* __restrict__ w_s1, unsigned short* __restrict__ s1h,
    const float* __restrict__ w_s2, unsigned short* __restrict__ s2h,
    const float* __restrict__ w_u3, const float* __restrict__ w_u4, unsigned short* __restrict__ u43h,
    const float* __restrict__ b_u3, const float* __restrict__ b_u4, float* __restrict__ b43,
    unsigned short* __restrict__ BfH, unsigned short* __restrict__ BfL,
    unsigned short* __restrict__ BfcH, unsigned short* __restrict__ BfcL,
    unsigned short* __restrict__ BicH, unsigned short* __restrict__ BicL,
    unsigned short* __restrict__ BirH, unsigned short* __restrict__ BirL,
    float* __restrict__ zbias,
    const float* __restrict__ w2, const float* __restrict__ b2,
    const float* __restrict__ w3, const float* __restrict__ b3,
    const float* __restrict__ wu2, const float* __restrict__ bu2,
    const float* __restrict__ wu1, const float* __restrict__ bu1,
    float* __restrict__ Wc, float* __restrict__ bc,
    float* __restrict__ W21c, float* __restrict__ b21c) {
    int b = blockIdx.x, tid = threadIdx.x;
    if (b < 128)       prep_one(w_d1, d1h, d1l, 128, 256, 6, b * 256 + tid);
    else if (b < 640)  prep_one(w_d2, d2h, d2l, 256, 512, 7, (b - 128) * 256 + tid);
    else if (b < 896)  prep_one(w_a1, a1h, a1l, 256, 256, 0, (b - 640) * 256 + tid);
    else if (b < 1152) prep_one(w_a2, a2h, a2l, 256, 256, 0, (b - 896) * 256 + tid);
    else if (b < 1408) prep_one(w_s1, s1h, nullptr, 256, 256, 0, (b - 1152) * 256 + tid);
    else if (b < 1664) prep_one(w_s2, s2h, nullptr, 256, 256, 0, (b - 1408) * 256 + tid);
    else if (b < 2384) bfft_one((b - 1664) * 256 + tid, BfH, BfL, BfcH, BfcL, BicH, BicL, BirH, BirL, zbias);
    else if (b < 2448) {
        int idx = (b - 2384) * 256 + tid;
        int n = idx >> 8, j = idx & 255;
        float s = 0.f;
        #pragma unroll 16
        for (int o = 0; o < 128; o++) s += w_u4[n * 128 + o] * w_u3[o * 256 + j];
        u43h[idx] = f2bf(s);
    } else {
        __shared__ float sWc[384], sW2c[384];
        if (tid < 128) {
            int j = tid;
            for (int r = 0; r < 3; r++) {
                float s = 0.f;
                #pragma unroll 16
                for (int o = 0; o < 64; o++) s += w3[r * 64 + o] * w2[o * 128 + j];
                sWc[r * 128 + j] = s;
                Wc[r * 128 + j] = s;
            }
            if (j < 3) {
                float s = b3[j];
                #pragma unroll 16
                for (int o = 0; o < 64; o++) s += w3[j * 64 + o] * b2[o];
                bc[j] = s;
            }
        }
        if (tid >= 128 && tid < 192) {
            int n = tid - 128;
            float s = b_u4[n];
            #pragma unroll 16
            for (int o = 0; o < 128; o++) s += w_u4[n * 128 + o] * b_u3[o];
            b43[n] = s;
        }
        __syncthreads();
        if (tid < 128) {
            int j = tid;
            for (int r = 0; r < 3; r++) {
                float s = 0.f;
                #pragma unroll 16
                for (int o = 0; o < 64; o++) s += sWc[r * 128 + o] * wu2[o * 128 + j];
                sW2c[r * 128 + j] = s;
            }
        }
        __syncthreads();
        if (tid < 256) {
            int j = tid;
            for (int r = 0; r < 3; r++) {
                float s = 0.f;
                #pragma unroll 16
                for (int o = 0; o < 128; o++) s += sW2c[r * 128 + o] * wu1[o * 256 + j];
                W21c[r * 256 + j] = s;
            }
        }
        if (tid < 3) {
            float s = 0.f;
            #pragma unroll 16
            for (int o = 0; o < 128; o++) s += sW2c[tid * 128 + o] * bu1[o];
            #pragma unroll 16
            for (int o = 0; o < 64; o++)  s += sWc[tid * 128 + o] * bu2[o];
            b21c[tid] = s;
        }
    }
}

// ---------------------------------------------------------------- x_f = e2(e1(x)), s2d [kord][m2] layout, bf16 out
__global__ __launch_bounds__(256) void k_ef2(const float* __restrict__ x,
                                             const float* __restrict__ w1, const float* __restrict__ b1,
                                             const float* __restrict__ w2, const float* __restrict__ b2,
                                             unsigned short* __restrict__ out) {
    __shared__ float sw1[24], sb1[8], sw2[512], sb2[64];
    int tid = threadIdx.x;
    if (tid < 24) sw1[tid] = w1[tid];
    if (tid < 8)  sb1[tid] = b1[tid];
    if (tid < 64) sb2[tid] = b2[tid];
    if (tid < 256) { sw2[tid] = w2[tid]; sw2[tid + 256] = w2[tid + 256]; }
    __syncthreads();
    int bid = blockIdx.x;
    int dydx = bid >> 8;
    int m2 = (bid & 255) * 256 + tid;
    int i = m2 >> 8, j = m2 & 255;
    int dy = dydx >> 1, dx = dydx & 1;
    int p5 = (2 * i + dy) * 512 + 2 * j + dx;
    float x0 = x[p5], x1 = x[p5 + NPIX], x2 = x[p5 + 2 * NPIX];
    float h[8];
    #pragma unroll
    for (int r = 0; r < 8; r++)
        h[r] = sw1[r * 3] * x0 + sw1[r * 3 + 1] * x1 + sw1[r * 3 + 2] * x2 + sb1[r];
    #pragma unroll 1
    for (int o = 0; o < 64; o++) {
        float acc = sb2[o];
        #pragma unroll
        for (int r = 0; r < 8; r++) acc += sw2[o * 8 + r] * h[r];
        out[(size_t)(dydx * 64 + o) * 65536 + m2] = f2bf(acc);
    }
}

// ---------------------------------------------------------------- channels-first MFMA GEMM
// C[n][m] (or TSTORE: C[m][n]) = sum_k B[n][k] * A(k, m) + bias[n]
// Launched as 1D grid (gx*gy); bijective XCD-chunk remap with y innermost so
// the gy blocks sharing an A strip run adjacent on the same XCD (L2 reuse).
template<int AMODE, int SPLIT, int LRELU, int TSTORE, int ABF16, int CBF16>
__global__ __launch_bounds__(256) void k_mmcf(const void* __restrict__ Asrc_,
                                              const unsigned short* __restrict__ Bh,
                                              const unsigned short* __restrict__ Bl,
                                              const float* __restrict__ bias, void* __restrict__ C_,
                                              int M, int N, int K, int cshift, int wshift, int srcW,
                                              int gy) {
    const float* Af = (const float*)Asrc_;
    const unsigned short* A16 = (const unsigned short*)Asrc_;
    float* Cf = (float*)C_;
    unsigned short* C16 = (unsigned short*)C_;
    __shared__ unsigned short AhS[128 * 40];
    __shared__ unsigned short BhS[64 * 40];
    __shared__ unsigned short AlS[SPLIT ? 128 * 40 : 8];
    __shared__ unsigned short BlS[SPLIT ? 64 * 40 : 8];
    int tid = threadIdx.x;
    // bijective XCD-chunk remap (m204 formula), y-inner work decomposition
    int nwg = (int)gridDim.x;
    int bid = blockIdx.x;
    int qq = nwg >> 3, rr = nwg & 7;
    int xcd = bid & 7, ixw = bid >> 3;
    int work = (xcd < rr) ? (xcd * (qq + 1) + ixw) : (rr * (qq + 1) + (xcd - rr) * qq + ixw);
    int bx = work / gy;
    int by = work - bx * gy;
    int m0 = bx * 128;
    int n0 = by * 64;
    int wave = tid >> 6, lane = tid & 63;
    int wm = (wave >> 1) * 64, wn = (wave & 1) * 32;
    int l15 = lane & 15, quad = lane >> 4;
    int lk = quad * 8, lk4 = quad * 4;
    fx4 acc[4][2];
    #pragma unroll
    for (int a = 0; a < 4; a++)
        #pragma unroll
        for (int b = 0; b < 2; b++)
            acc[a][b] = (fx4){0.f, 0.f, 0.f, 0.f};

    int mm = tid & 127;
    int kpb = tid >> 7;
    int gm = m0 + mm;
    int oj = 0, oi = 0, cA = 0, kfA = 0, tauA = 0;
    size_t abase = 0;
    if (AMODE == 1) { oj = gm & ((1 << wshift) - 1); oi = gm >> wshift; }
    if (AMODE == 3) abase = (size_t)gm * K;
    if (AMODE == 7) { cA = gm / 65; kfA = gm - cA * 65; }
    if (AMODE == 8) { cA = gm >> 7; tauA = gm & 127; }

    for (int kb = 0; kb < K; kb += 32) {
        if (AMODE == 3 && ABF16 && !SPLIT) {
            // contiguous-in-k source: direct 16B vector loads
            #pragma unroll
            for (int half = 0; half < 2; half++) {
                sh8 hv = *(const sh8*)(const void*)&A16[abase + kb + kpb * 16 + half * 8];
                *(sh8*)(void*)&AhS[mm * 40 + (kpb * 2 + half) * 8] = hv;
            }
        } else {
            #pragma unroll
            for (int half = 0; half < 2; half++) {
                sh8 hv, lv;
                #pragma unroll
                for (int tt = 0; tt < 4; tt++) {
                    int kp = kpb * 8 + half * 4 + tt;
                    int k0 = kb + kp * 2;
                    size_t ad0, ad1;
                    if (AMODE == 0) {
                        ad0 = (size_t)k0 * M + gm;
                        ad1 = ad0 + M;
                    } else if (AMODE == 1) {
                        int c = k0 & ((1 << cshift) - 1);
                        int dydx = k0 >> cshift;
                        int dy = dydx >> 1, dx = dydx & 1;
                        size_t pix = (size_t)(2 * oi + dy) * srcW + (2 * oj + dx);
                        size_t plane = (size_t)srcW * srcW;
                        ad0 = (size_t)c * plane + pix;
                        ad1 = ad0 + plane;
                    } else if (AMODE == 3) {
                        ad0 = abase + k0;
                        ad1 = ad0 + 1;
                    } else if (AMODE == 7) {
                        int t0 = k0 & 127, hf = k0 >> 7;
                        ad0 = (size_t)(cA * 128 + t0) * 256 + hf * 128 + kfA;
                        ad1 = ad0 + 256;
                    } else {                       // AMODE 8
                        int j0 = k0, j1 = k0 + 1;
                        int kf0 = (j0 < 65) ? j0 : ((j0 < 130) ? j0 - 65 : 0);
                        int hf0 = (j0 >= 65 && j0 < 130) ? 1 : 0;
                        int kf1 = (j1 < 65) ? j1 : ((j1 < 130) ? j1 - 65 : 0);
                        int hf1 = (j1 >= 65 && j1 < 130) ? 1 : 0;
                        ad0 = (size_t)(cA * 65 + kf0) * 256 + hf0 * 128 + tauA;
                        ad1 = (size_t)(cA * 65 + kf1) * 256 + hf1 * 128 + tauA;
                    }
                    unsigned short h0, h1;
                    if (ABF16) {
                        h0 = A16[ad0];
                        h1 = A16[ad1];
                    } else {
                        float a0 = Af[ad0], a1 = Af[ad1];
                        h0 = f2bf(a0);
                        h1 = f2bf(a1);
                        if (SPLIT) {
                            lv[tt * 2] = (short)f2bf(a0 - bf2f(h0));
                            lv[tt * 2 + 1] = (short)f2bf(a1 - bf2f(h1));
                        }
                    }
                    hv[tt * 2] = (short)h0;
                    hv[tt * 2 + 1] = (short)h1;
                }
                int coff = (kpb * 2 + half) * 8;
                *(sh8*)(void*)&AhS[mm * 40 + coff] = hv;
                if (SPLIT) *(sh8*)(void*)&AlS[mm * 40 + coff] = lv;
            }
        }
        {
            int n = tid >> 2, seg = tid & 3;
            size_t gb = (size_t)(n0 + n) * K + kb + seg * 8;
            *(sh8*)(void*)&BhS[n * 40 + seg * 8] = *(const sh8*)(const void*)&Bh[gb];
            if (SPLIT) *(sh8*)(void*)&BlS[n * 40 + seg * 8] = *(const sh8*)(const void*)&Bl[gb];
        }
        __syncthreads();
        sh8 af[4], bf[2], afl[4], bfl[2];
        #pragma unroll
        for (int mt = 0; mt < 4; mt++) {
            af[mt] = *(const sh8*)(const void*)&AhS[(wm + mt * 16 + l15) * 40 + lk];
            if (SPLIT) afl[mt] = *(const sh8*)(const void*)&AlS[(wm + mt * 16 + l15) * 40 + lk];
        }
        #pragma unroll
        for (int nt = 0; nt < 2; nt++) {
            bf[nt] = *(const sh8*)(const void*)&BhS[(wn + nt * 16 + l15) * 40 + lk];
            if (SPLIT) bfl[nt] = *(const sh8*)(const void*)&BlS[(wn + nt * 16 + l15) * 40 + lk];
        }
        #pragma unroll
        for (int mt = 0; mt < 4; mt++)
            #pragma unroll
            for (int nt = 0; nt < 2; nt++) {
                acc[mt][nt] = __builtin_amdgcn_mfma_f32_16x16x32_bf16(af[mt], bf[nt], acc[mt][nt], 0, 0, 0);
                if (SPLIT) {
                    acc[mt][nt] = __builtin_amdgcn_mfma_f32_16x16x32_bf16(af[mt], bfl[nt], acc[mt][nt], 0, 0, 0);
                    acc[mt][nt] = __builtin_amdgcn_mfma_f32_16x16x32_bf16(afl[mt], bf[nt], acc[mt][nt], 0, 0, 0);
                }
            }
        __syncthreads();
    }
    #pragma unroll
    for (int nt = 0; nt < 2; nt++) {
        int n = n0 + wn + nt * 16 + l15;
        float bs = bias[n];
        #pragma unroll
        for (int mt = 0; mt < 4; mt++) {
            int mbase = m0 + wm + mt * 16 + lk4;
            if (TSTORE) {
                #pragma unroll
                for (int r = 0; r < 4; r++) {
                    float q = acc[mt][nt][r] + bs;
                    if (LRELU) q = (q < 0.f) ? 0.1f * q : q;
                    if (CBF16) C16[(size_t)(mbase + r) * N + n] = f2bf(q);
                    else       Cf[(size_t)(mbase + r) * N + n] = q;
                }
            } else if (CBF16) {
                ush4 v;
                #pragma unroll
                for (int r = 0; r < 4; r++) {
                    float q = acc[mt][nt][r] + bs;
                    if (LRELU) q = (q < 0.f) ? 0.1f * q : q;
                    v[r] = f2bf(q);
                }
                *(ush4*)(void*)&C16[(size_t)n * M + mbase] = v;
            } else {
                float4 v;
                float* vp = (float*)&v;
                #pragma unroll
                for (int r = 0; r < 4; r++) {
                    float q = acc[mt][nt][r] + bs;
                    if (LRELU) q = (q < 0.f) ? 0.1f * q : q;
                    vp[r] = q;
                }
                *(float4*)&Cf[(size_t)n * M + mbase] = v;
            }
        }
    }
}

// ---------------------------------------------------------------- amp = sqrt(re^2+im^2), flattened full-wave
__global__ __launch_bounds__(256) void k_ampc(const float* __restrict__ F2C, float* __restrict__ ampb) {
    int idx = blockIdx.x * 256 + threadIdx.x;   // < 2129920 = 256*128*65
    int ct = idx / 65, kf = idx - ct * 65;
    int c = ct >> 7, t = ct & 127;
    size_t m = (size_t)c * 65 + kf;
    float re = F2C[(size_t)t * 16640 + m];
    float im = F2C[(size_t)(t + 128) * 16640 + m];
    ampb[idx] = sqrtf(re * re + im * im);
}

// ---------------------------------------------------------------- z = a*(cos a, sin a), flattened full-wave, bf16
__global__ __launch_bounds__(256) void k_zbuild(const float* __restrict__ A2, unsigned short* __restrict__ Z) {
    int idx = blockIdx.x * 256 + threadIdx.x;   // < 2129920
    int ct = idx / 65, kf = idx - ct * 65;
    int c = ct >> 7, t = ct & 127;
    float a = A2[idx];
    float s_, c_;
    sincosf(a, &s_, &c_);
    size_t m = (size_t)c * 65 + kf;
    Z[(size_t)t * 16640 + m] = f2bf(a * c_);
    Z[2129920 + (size_t)t * 16640 + m] = f2bf(a * s_);
}

// ---------------------------------------------------------------- h3s = W21c @ I2T + b21c  (3ch @128^2, K=256)
__global__ __launch_bounds__(64) void k_h3s(const float* __restrict__ I2T, const float* __restrict__ W21c,
                                            const float* __restrict__ b21c, float* __restrict__ h3s) {
    __shared__ float wa[768], bs[3];
    int tid = threadIdx.x;
    for (int i = tid; i < 768; i += 64) wa[i] = W21c[i];
    if (tid < 3) bs[tid] = b21c[tid];
    __syncthreads();
    int q = blockIdx.x * 64 + tid;
    float a0 = bs[0], a1 = bs[1], a2 = bs[2];
    #pragma unroll 4
    for (int c = 0; c < 256; c++) {
        float v = I2T[(size_t)c * 16384 + q];
        a0 += wa[c] * v;
        a1 += wa[256 + c] * v;
        a2 += wa[512 + c] * v;
    }
    h3s[q] = a0; h3s[16384 + q] = a1; h3s[32768 + q] = a2;
}

// ---------------------------------------------------------------- channels-first bilinear x2 resize
__global__ __launch_bounds__(256) void k_resize2(const float* __restrict__ src, float* __restrict__ dst,
                                                 int C, int H) {
    int W2 = 2 * H;
    size_t idx = (size_t)blockIdx.x * 256 + threadIdx.x;
    size_t plane = (size_t)W2 * W2;
    if (idx >= (size_t)C * plane) return;
    int c = (int)(idx / plane);
    int rem = (int)(idx - (size_t)c * plane);
    int i = rem / W2, j = rem - i * W2;
    int ky = i >> 1, ylo, yhi; float wyl, wyh;
    if ((i & 1) == 0) { ylo = ky - 1; yhi = ky; wyl = .25f; wyh = .75f; if (ylo < 0) { ylo = 0; wyl = 0.f; wyh = 1.f; } }
    else              { ylo = ky; yhi = ky + 1; wyl = .75f; wyh = .25f; if (yhi > H - 1) { yhi = H - 1; wyh = 0.f; wyl = 1.f; } }
    int kx = j >> 1, xlo, xhi; float wxl, wxh;
    if ((j & 1) == 0) { xlo = kx - 1; xhi = kx; wxl = .25f; wxh = .75f; if (xlo < 0) { xlo = 0; wxl = 0.f; wxh = 1.f; } }
    else              { xlo = kx; xhi = kx + 1; wxl = .75f; wxh = .25f; if (xhi > H - 1) { xhi = H - 1; wxh = 0.f; wxl = 1.f; } }
    const float* p = src + (size_t)c * H * H;
    dst[idx] = wyl * (wxl * p[(size_t)ylo * H + xlo] + wxh * p[(size_t)ylo * H + xhi]) +
               wyh * (wxl * p[(size_t)yhi * H + xlo] + wxh * p[(size_t)yhi * H + xhi]);
}

// ---------------------------------------------------------------- final fused stage @512^2
__global__ __launch_bounds__(256) void k_final(const float* __restrict__ x,
                                               const float* __restrict__ dark, const int* __restrict__ gmax,
                                               const float* __restrict__ wcf1, const float* __restrict__ bcf1,
                                               const float* __restrict__ Wc, const float* __restrict__ bc,
                                               const float* __restrict__ g4, const float* __restrict__ h3,
                                               float* __restrict__ out) {
    __shared__ float dimt[32], w1[192], b1[64], wb[192], bcs[3];
    int tid = threadIdx.x;
    if (tid < 32) dimt[tid] = powf(10000.f, (float)(2 * (tid >> 1)) / 32.f);
    if (tid < 192) w1[tid] = wcf1[tid];
    if (tid < 64) b1[tid] = bcf1[tid];
    if (tid < 192) { int r = tid / 64, c = tid - (tid / 64) * 64; wb[tid] = Wc[r * 128 + 64 + c]; }
    if (tid < 3) bcs[tid] = bc[tid];
    __syncthreads();
    int p = blockIdx.x * 256 + threadIdx.x;
    int i = p >> 9, j = p & 511;
    const float scale = 2.f * PI_F;
    float inv511 = scale / (511.f + 1e-6f);
    float xe = (float)j * inv511, ye = (float)i * inv511;
    float gm = __int_as_float(gmax[0]);
    float ze = dark[p] / (gm + 1e-6f) * scale;
    float x0 = x[p], x1 = x[p + NPIX], x2 = x[p + 2 * NPIX];

    int ky = i >> 1, ylo, yhi; float wyl, wyh;
    if ((i & 1) == 0) { ylo = ky - 1; yhi = ky; wyl = .25f; wyh = .75f; if (ylo < 0) { ylo = 0; wyl = 0.f; wyh = 1.f; } }
    else              { ylo = ky; yhi = ky + 1; wyl = .75f; wyh = .25f; if (yhi > 255) { yhi = 255; wyh = 0.f; wyl = 1.f; } }
    int kx = j >> 1, xlo, xhi; float wxl, wxh;
    if ((j & 1) == 0) { xlo = kx - 1; xhi = kx; wxl = .25f; wxh = .75f; if (xlo < 0) { xlo = 0; wxl = 0.f; wxh = 1.f; } }
    else              { xlo = kx; xhi = kx + 1; wxl = .75f; wxh = .25f; if (xhi > 255) { xhi = 255; wxh = 0.f; wxl = 1.f; } }
    int s00 = ylo * 256 + xlo, s01 = ylo * 256 + xhi, s10 = yhi * 256 + xlo, s11 = yhi * 256 + xhi;
    float w00 = wyl * wxl, w01 = wyl * wxh, w10 = wyh * wxl, w11 = wyh * wxh;

    float a0 = 0.f, a1 = 0.f, a2 = 0.f;
    #pragma unroll 1
    for (int c = 0; c < 64; c++) {
        float e = (c < 16) ? xe / dimt[c] : (c < 32) ? ye / dimt[c - 16] : ze / dimt[c - 32];
        float sn, cs;
        __sincosf(e, &sn, &cs);
        float pos = ((c & 1) == 0) ? sn : cs;
        float ape = pos + w1[c * 3] * x0 + w1[c * 3 + 1] * x1 + w1[c * 3 + 2] * x2 + b1[c];
        const float* gp = g4 + (size_t)c * 65536;
        float gv = w00 * gp[s00] + w01 * gp[s01] + w10 * gp[s10] + w11 * gp[s11];
        float s = gv * ape;
        a0 += wb[c] * s; a1 += wb[64 + c] * s; a2 += wb[128 + c] * s;
    }
    float f0 = w00 * h3[s00] + w01 * h3[s01] + w10 * h3[s10] + w11 * h3[s11];
    const float* h1 = h3 + 65536;
    float f1 = w00 * h1[s00] + w01 * h1[s01] + w10 * h1[s10] + w11 * h1[s11];
    const float* h2 = h3 + 131072;
    float f2 = w00 * h2[s00] + w01 * h2[s01] + w10 * h2[s10] + w11 * h2[s11];
    out[p]            = a0 + f0 + bcs[0] + x0;
    out[NPIX + p]     = a1 + f1 + bcs[1] + x1;
    out[2 * NPIX + p] = a2 + f2 + bcs[2] + x2;
}

// ================================================================ launcher
extern "C" void kernel_launch(void* const* d_in, const int* in_sizes, int n_in,
                              void* d_out, int out_size, void* d_ws, size_t ws_size,
                              hipStream_t stream) {
    const float* x      = (const float*)d_in[0];
    const float* w_cf1  = (const float*)d_in[1];  const float* b_cf1 = (const float*)d_in[2];
    const float* w_e1   = (const float*)d_in[3];  const float* b_e1  = (const float*)d_in[4];
    const float* w_e2   = (const float*)d_in[5];  const float* b_e2  = (const float*)d_in[6];
    const float* w_d1   = (const float*)d_in[7];  const float* b_d1  = (const float*)d_in[8];
    const float* w_d2   = (const float*)d_in[9];  const float* b_d2  = (const float*)d_in[10];
    // 11..14: pha branch is dead code in the reference
    const float* w_amp1 = (const float*)d_in[15]; const float* b_amp1 = (const float*)d_in[16];
    const float* w_amp2 = (const float*)d_in[17]; const float* b_amp2 = (const float*)d_in[18];
    const float* w_sp1  = (const float*)d_in[19]; const float* b_sp1  = (const float*)d_in[20];
    const float* w_sp2  = (const float*)d_in[21]; const float* b_sp2  = (const float*)d_in[22];
    const float* w_u1   = (const float*)d_in[23]; const float* b_u1   = (const float*)d_in[24];
    const float* w_u2   = (const float*)d_in[25]; const float* b_u2   = (const float*)d_in[26];
    const float* w_u3   = (const float*)d_in[27]; const float* b_u3   = (const float*)d_in[28];
    const float* w_u4   = (const float*)d_in[29]; const float* b_u4   = (const float*)d_in[30];
    const float* w_cf2  = (const float*)d_in[31]; const float* b_cf2  = (const float*)d_in[32];
    const float* w_cf3  = (const float*)d_in[33]; const float* b_cf3  = (const float*)d_in[34];
    float* out = (float*)d_out;

    char* ws = (char*)d_ws;
    constexpr size_t MiB = 1ull << 20;
    float*  dark   = (float*)(ws + 0 * MiB);
    float*  tmp    = (float*)(ws + 1 * MiB);
    int*    gmax   = (int*)  (ws + 2 * MiB);
    float*  Wc     = (float*)(ws + 2 * MiB + 1024);
    float*  bc     = (float*)(ws + 2 * MiB + 2560);
    float*  W21c   = (float*)(ws + 2 * MiB + 4096);
    float*  b21c   = (float*)(ws + 2 * MiB + 7168);
    float*  b43    = (float*)(ws + 2 * MiB + 7424);
    unsigned short* xfs = (unsigned short*)(ws + 3 * MiB);    // bf16 [256][65536] = 32 MiB
    unsigned short* xd1 = (unsigned short*)(ws + 67 * MiB);   // bf16 [128][65536] = 16 MiB
    unsigned short* xd2 = (unsigned short*)(ws + 99 * MiB);   // bf16 [256][16384] =  8 MiB
    unsigned short* F1T = (unsigned short*)(ws + 115 * MiB);  // bf16 [32768][256] = 16 MiB
    float*  F2C    = (float*)(ws + 147 * MiB);                // fp32 (feeds sqrt)
    float*  ampb   = (float*)(ws + 164 * MiB);                // fp32 (split MLP)
    float*  A1     = (float*)(ws + 173 * MiB);
    float*  A2     = (float*)(ws + 182 * MiB);
    unsigned short* Zbuf = (unsigned short*)(ws + 115 * MiB); // bf16 (F1T dead after F2)
    unsigned short* I1T  = (unsigned short*)(ws + 132 * MiB); // bf16 [16640][256] = 8.5 MiB
    float*  I2T    = (float*)(ws + 149 * MiB);                // fp32 (feeds h3s fp32 dot)
    float*  h3s    = (float*)(ws + 11 * MiB);
    float*  h3     = (float*)(ws + 27 * MiB);
    unsigned short* s1 = (unsigned short*)(ws + 31 * MiB);    // bf16 [256][16384] = 8 MiB
    unsigned short* s2 = (unsigned short*)(ws + 47 * MiB);    // bf16
    float*  g4out  = (float*)(ws + 71 * MiB);
    float*  g4s    = (float*)(ws + 87 * MiB);
    unsigned short* wb16 = (unsigned short*)(ws + 192 * MiB);
    unsigned short* d1h = wb16 + 0,       * d1l = wb16 + 32768;
    unsigned short* d2h = wb16 + 65536,   * d2l = wb16 + 196608;
    unsigned short* a1h = wb16 + 327680,  * a1l = wb16 + 393216;
    unsigned short* a2h = wb16 + 458752,  * a2l = wb16 + 524288;
    unsigned short* s1h = wb16 + 589824;
    unsigned short* s2h = wb16 + 655360;
    unsigned short* u43h = wb16 + 720896;
    unsigned short* BfH = wb16 + 786432,  * BfL = wb16 + 819200;
    unsigned short* BfcH = wb16 + 851968, * BfcL = wb16 + 917504;
    unsigned short* BicH = wb16 + 983040, * BicL = wb16 + 1048576;
    unsigned short* BirH = wb16 + 1114112,* BirL = wb16 + 1134592;
    float* zbias = (float*)(ws + 195 * MiB + 512 * 1024);

    // 1) dark channel + gmax ; merged prep
    k_mrow<<<512, 256, 0, stream>>>(x, tmp, gmax);
    k_mincol_max<<<1024, 256, 0, stream>>>(tmp, dark, gmax);
    k_prep<<<2449, 256, 0, stream>>>(
        w_d1, d1h, d1l, w_d2, d2h, d2l, w_amp1, a1h, a1l, w_amp2, a2h, a2l,
        w_sp1, s1h, w_sp2, s2h,
        w_u3, w_u4, u43h, b_u3, b_u4, b43,
        BfH, BfL, BfcH, BfcL, BicH, BicL, BirH, BirL, zbias,
        w_cf2, b_cf2, w_cf3, b_cf3, w_u2, b_u2, w_u1, b_u1, Wc, bc, W21c, b21c);

    // 2) e1/e2 in s2d layout (bf16 out) ; d1 ; d2 — all-bf16 intermediate chain
    k_ef2<<<1024, 256, 0, stream>>>(x, w_e1, b_e1, w_e2, b_e2, xfs);
    k_mmcf<0, 0, 0, 0, 1, 1><<<1024, 256, 0, stream>>>(xfs, d1h, nullptr, b_d1, xd1, 65536, 128, 256, 0, 0, 0, 2);
    k_mmcf<1, 0, 0, 0, 1, 1><<<512, 256, 0, stream>>>(xd1, d2h, nullptr, b_d2, xd2, 16384, 256, 512, 7, 7, 256, 4);

    // 3) FFT section (bf16 DFT GEMMs; amp MLP stays fp32 split-bf16 for phase safety)
    k_mmcf<3, 0, 0, 1, 1, 1><<<1024, 256, 0, stream>>>(xd2, BfH, nullptr, zbias, F1T, 32768, 256, 128, 0, 0, 0, 4);
    k_mmcf<7, 0, 0, 0, 1, 0><<<520, 256, 0, stream>>>(F1T, BfcH, nullptr, zbias, F2C, 16640, 256, 256, 0, 0, 0, 4);
    k_ampc<<<8320, 256, 0, stream>>>(F2C, ampb);
    k_mmcf<0, 1, 1, 0, 0, 0><<<260, 256, 0, stream>>>(ampb, a1h, a1l, b_amp1, A1, 8320, 256, 256, 0, 0, 0, 4);
    k_mmcf<0, 1, 0, 0, 0, 0><<<260, 256, 0, stream>>>(A1, a2h, a2l, b_amp2, A2, 8320, 256, 256, 0, 0, 0, 4);
    k_zbuild<<<8320, 256, 0, stream>>>(A2, Zbuf);
    k_mmcf<0, 0, 0, 1, 1, 1><<<520, 256, 0, stream>>>(Zbuf, BicH, nullptr, zbias, I1T, 16640, 256, 256, 0, 0, 0, 4);
    k_mmcf<8, 0, 0, 1, 1, 0><<<512, 256, 0, stream>>>(I1T, BirH, nullptr, zbias, I2T, 32768, 128, 160, 0, 0, 0, 2);

    // 4) four path: h3s = W21c @ I2T ; resize 3ch
    k_h3s<<<256, 64, 0, stream>>>(I2T, W21c, b21c, h3s);
    k_resize2<<<768, 256, 0, stream>>>(h3s, h3, 3, 128);

    // 5) spat path: sp1, sp2, composed u43 GEMM ; resize 64ch
    k_mmcf<0, 0, 1, 0, 1, 1><<<512, 256, 0, stream>>>(xd2, s1h, nullptr, b_sp1, s1, 16384, 256, 256, 0, 0, 0, 4);
    k_mmcf<0, 0, 0, 0, 1, 1><<<512, 256, 0, stream>>>(s1, s2h, nullptr, b_sp2, s2, 16384, 256, 256, 0, 0, 0, 4);
    k_mmcf<0, 0, 0, 0, 1, 0><<<128, 256, 0, stream>>>(s2, u43h, nullptr, b43, g4s, 16384, 64, 256, 0, 0, 0, 1);
    k_resize2<<<16384, 256, 0, stream>>>(g4s, g4out, 64, 128);

    // 6) final fused stage
    k_final<<<1024, 256, 0, stream>>>(x, dark, gmax, w_cf1, b_cf1, Wc, bc, g4out, h3, out);
}

// Round 3
// 388.542 us; speedup vs baseline: 1.1389x; 1.0288x over previous
//
#include <hip/hip_runtime.h>
#include <math.h>

#define PI_F 3.14159265358979323846f
#define NPIX 262144   // 512*512

typedef __attribute__((ext_vector_type(8))) short sh8;
typedef __attribute__((ext_vector_type(4))) float fx4;
typedef __attribute__((ext_vector_type(4))) unsigned short ush4;

__device__ __forceinline__ unsigned short f2bf(float v) {
    unsigned u = __float_as_uint(v);
    return (unsigned short)((u + 0x7FFFu + ((u >> 16) & 1)) >> 16);
}
__device__ __forceinline__ float bf2f(unsigned short h) {
    return __uint_as_float((unsigned)h << 16);
}

__device__ __forceinline__ int refl512(int t) {
    if (t < 0) t = -t;
    if (t > 511) t = 1022 - t;
    return t;
}

// ---------------------------------------------------------------- dark channel (fused min-c + row-min)
__global__ __launch_bounds__(256) void k_mrow(const float* __restrict__ x, float* __restrict__ tmp,
                                              int* __restrict__ gmax) {
    __shared__ float row[512];
    int i = blockIdx.x, tid = threadIdx.x;
    if (i == 0 && tid == 0) gmax[0] = 0;
    #pragma unroll
    for (int h = 0; h < 2; h++) {
        int j = tid + h * 256;
        int p = (i << 9) + j;
        float m = fmaxf(x[p], fmaxf(x[p + NPIX], x[p + 2 * NPIX]));
        row[j] = 1.0f - m;
    }
    __syncthreads();
    #pragma unroll
    for (int h = 0; h < 2; h++) {
        int j = tid + h * 256;
        float m = 1e30f;
        #pragma unroll
        for (int d = -7; d <= 7; d++) m = fminf(m, row[refl512(j + d)]);
        tmp[(i << 9) + j] = m;
    }
}

__global__ __launch_bounds__(256) void k_mincol_max(const float* __restrict__ tmp, float* __restrict__ dark,
                                                    int* __restrict__ gmax) {
    int p = blockIdx.x * 256 + threadIdx.x;
    int i = p >> 9, j = p & 511;
    float m = 1e30f;
    #pragma unroll
    for (int d = -7; d <= 7; d++) m = fminf(m, tmp[(refl512(i + d) << 9) + j]);
    dark[p] = m;
    __shared__ float red[256];
    int tid = threadIdx.x;
    red[tid] = m;
    __syncthreads();
    for (int s = 128; s > 0; s >>= 1) {
        if (tid < s) red[tid] = fmaxf(red[tid], red[tid + s]);
        __syncthreads();
    }
    if (tid == 0) atomicMax(gmax, __float_as_int(red[0]));
}

// ---------------------------------------------------------------- prep helpers (device)
__device__ __forceinline__ void prep_one(const float* __restrict__ w, unsigned short* __restrict__ h,
                                         unsigned short* __restrict__ l, int N, int K, int cshift, int idx) {
    if (idx >= N * K) return;
    int n = idx / K, kord = idx - n * K;
    int ksrc = kord;
    if (cshift) {
        int dydx = kord >> cshift, c = kord & ((1 << cshift) - 1);
        ksrc = c * 4 + dydx;
    }
    float v = w[n * K + ksrc];
    unsigned short hb = f2bf(v);
    h[idx] = hb;
    if (l) l[idx] = f2bf(v - bf2f(hb));
}

__device__ __forceinline__ void bfft_one(int idx,
                                         unsigned short* __restrict__ BfH, unsigned short* __restrict__ BfL,
                                         unsigned short* __restrict__ BfcH, unsigned short* __restrict__ BfcL,
                                         unsigned short* __restrict__ BicH, unsigned short* __restrict__ BicL,
                                         unsigned short* __restrict__ BirH, unsigned short* __restrict__ BirL,
                                         float* __restrict__ zbias) {
    if (idx < 256) zbias[idx] = 0.f;
    const float w0 = 2.f * PI_F / 128.f;
    float v;
    unsigned short *H, *L;
    int off;
    if (idx < 32768) {                     // Bf [256][128]
        int n = idx >> 7, k = idx & 127;
        int t = n & 127, r = (t * k) & 127;
        float s_, c_; sincosf(w0 * r, &s_, &c_);
        v = (n < 128) ? c_ : -s_;
        H = BfH; L = BfL; off = idx;
    } else if (idx < 98304) {              // Bfc [256][256]
        int i = idx - 32768;
        int n = i >> 8, j = i & 255;
        int t = n & 127, r = (t * (j & 127)) & 127;
        float s_, c_; sincosf(w0 * r, &s_, &c_);
        v = (n < 128) ? ((j < 128) ? c_ : s_) : ((j < 128) ? -s_ : c_);
        H = BfcH; L = BfcL; off = i;
    } else if (idx < 163840) {             // Bic [256][256]
        int i = idx - 98304;
        int n = i >> 8, j = i & 255;
        int t = n & 127, r = (t * (j & 127)) & 127;
        float s_, c_; sincosf(w0 * r, &s_, &c_);
        v = ((n < 128) ? ((j < 128) ? c_ : -s_) : ((j < 128) ? s_ : c_)) * (1.f / 128.f);
        H = BicH; L = BicL; off = i;
    } else if (idx < 184320) {             // Bir [128][160]
        int i = idx - 163840;
        int col = i / 160, j = i - col * 160;
        if (j == 0) v = 1.f / 128.f;
        else if (j < 64)  { int r = (j * col) & 127; float s_, c_; sincosf(w0 * r, &s_, &c_); v = 2.f * c_ / 128.f; }
        else if (j == 64) v = (col & 1) ? -1.f / 128.f : 1.f / 128.f;
        else if (j >= 66 && j <= 128) { int k = j - 65; int r = (k * col) & 127; float s_, c_; sincosf(w0 * r, &s_, &c_); v = -2.f * s_ / 128.f; }
        else v = 0.f;
        H = BirH; L = BirL; off = i;
    } else return;
    unsigned short hb = f2bf(v);
    H[off] = hb;
    L[off] = f2bf(v - bf2f(hb));
}

// ---------------------------------------------------------------- merged prep kernel
__global__ __launch_bounds__(256) void k_prep(
    const float* __restrict__ w_e1, const float* __restrict__ b_e1,
    const float* __restrict__ w_e2, const float* __restrict__ b_e2,
    const float* __restrict__ w_d1, const float* __restrict__ b_d1,
    unsigned short* __restrict__ d1ch, float* __restrict__ b1c,
    const float* __restrict__ w_d2, unsigned short* __restrict__ d2h, unsigned short* __restrict__ d2l,
    const float* __restrict__ w_a1, unsigned short* __restrict__ a1h, unsigned short* __restrict__ a1l,
    const float* __restrict__ w_a2, unsigned short* __restrict__ a2h, unsigned short* __restrict__ a2l,
    const float* __restrict__ w_s1, unsigned short* __restrict__ s1h,
    const float* __restrict__ w_u3, const float* __restrict__ w_u4, float* __restrict__ Uf,
    const float* __restrict__ b_u3, const float* __restrict__ b_u4, float* __restrict__ b43,
    unsigned short* __restrict__ BfH, unsigned short* __restrict__ BfL,
    unsigned short* __restrict__ BfcH, unsigned short* __restrict__ BfcL,
    unsigned short* __restrict__ BicH, unsigned short* __restrict__ BicL,
    unsigned short* __restrict__ BirH, unsigned short* __restrict__ BirL,
    float* __restrict__ zbias,
    const float* __restrict__ w2, const float* __restrict__ b2,
    const float* __restrict__ w3, const float* __restrict__ b3,
    const float* __restrict__ wu2, const float* __restrict__ bu2,
    const float* __restrict__ wu1, const float* __restrict__ bu1,
    float* __restrict__ Wc, float* __restrict__ bc,
    float* __restrict__ W21c, float* __restrict__ b21c) {
    int b = blockIdx.x, tid = threadIdx.x;
    if (b == 0) {
        // compose W'' = w_d1 ∘ w_e2 ∘ w_e1 : [128][12] (padded to 32), b'' fold
        __shared__ float E[192], f[64];
        if (tid < 192) {
            int o = tid / 3, ci = tid - o * 3;
            float s = 0.f;
            #pragma unroll
            for (int r = 0; r < 8; r++) s += w_e2[o * 8 + r] * w_e1[r * 3 + ci];
            E[tid] = s;
        }
        if (tid >= 192 && tid < 256) {
            int o = tid - 192;
            float s = b_e2[o];
            #pragma unroll
            for (int r = 0; r < 8; r++) s += w_e2[o * 8 + r] * b_e1[r];
            f[o] = s;
        }
        __syncthreads();
        for (int idx = tid; idx < 4096; idx += 256) {
            int n = idx >> 5, k = idx & 31;
            float s = 0.f;
            if (k < 12) {
                int dydx = k / 3, ci = k - dydx * 3;
                #pragma unroll 16
                for (int o = 0; o < 64; o++) s += w_d1[n * 256 + o * 4 + dydx] * E[o * 3 + ci];
            }
            d1ch[idx] = f2bf(s);
        }
        if (tid < 128) {
            float s = b_d1[tid];
            for (int o = 0; o < 64; o++) {
                float fo = f[o];
                #pragma unroll
                for (int dydx = 0; dydx < 4; dydx++) s += w_d1[tid * 256 + o * 4 + dydx] * fo;
            }
            b1c[tid] = s;
        }
    }
    else if (b < 513)  prep_one(w_d2, d2h, d2l, 256, 512, 7, (b - 1) * 256 + tid);
    else if (b < 769)  prep_one(w_a1, a1h, a1l, 256, 256, 0, (b - 513) * 256 + tid);
    else if (b < 1025) prep_one(w_a2, a2h, a2l, 256, 256, 0, (b - 769) * 256 + tid);
    else if (b < 1281) prep_one(w_s1, s1h, nullptr, 256, 256, 0, (b - 1025) * 256 + tid);
    else if (b < 2001) bfft_one((b - 1281) * 256 + tid, BfH, BfL, BfcH, BfcL, BicH, BicL, BirH, BirL, zbias);
    else if (b < 2065) {
        int idx = (b - 2001) * 256 + tid;
        int n = idx >> 8, j = idx & 255;
        float s = 0.f;
        #pragma unroll 16
        for (int o = 0; o < 128; o++) s += w_u4[n * 128 + o] * w_u3[o * 256 + j];
        Uf[idx] = s;                       // fp32: feeds Wg compose in k_prep2
    } else {
        __shared__ float sWc[384], sW2c[384];
        if (tid < 128) {
            int j = tid;
            for (int r = 0; r < 3; r++) {
                float s = 0.f;
                #pragma unroll 16
                for (int o = 0; o < 64; o++) s += w3[r * 64 + o] * w2[o * 128 + j];
                sWc[r * 128 + j] = s;
                Wc[r * 128 + j] = s;
            }
            if (j < 3) {
                float s = b3[j];
                #pragma unroll 16
                for (int o = 0; o < 64; o++) s += w3[j * 64 + o] * b2[o];
                bc[j] = s;
            }
        }
        if (tid >= 128 && tid < 192) {
            int n = tid - 128;
            float s = b_u4[n];
            #pragma unroll 16
            for (int o = 0; o < 128; o++) s += w_u4[n * 128 + o] * b_u3[o];
            b43[n] = s;
        }
        __syncthreads();
        if (tid < 128) {
            int j = tid;
            for (int r = 0; r < 3; r++) {
                float s = 0.f;
                #pragma unroll 16
                for (int o = 0; o < 64; o++) s += sWc[r * 128 + o] * wu2[o * 128 + j];
                sW2c[r * 128 + j] = s;
            }
        }
        __syncthreads();
        if (tid < 256) {
            int j = tid;
            for (int r = 0; r < 3; r++) {
                float s = 0.f;
                #pragma unroll 16
                for (int o = 0; o < 128; o++) s += sW2c[r * 128 + o] * wu1[o * 256 + j];
                W21c[r * 256 + j] = s;
            }
        }
        if (tid < 3) {
            float s = 0.f;
            #pragma unroll 16
            for (int o = 0; o < 128; o++) s += sW2c[tid * 128 + o] * bu1[o];
            #pragma unroll 16
            for (int o = 0; o < 64; o++)  s += sWc[tid * 128 + o] * bu2[o];
            b21c[tid] = s;
        }
    }
}

// ---------------------------------------------------------------- Wg = (u4·u3)·w_sp2 compose, b_g fold
__global__ __launch_bounds__(256) void k_prep2(const float* __restrict__ Uf, const float* __restrict__ wsp2,
                                               const float* __restrict__ bsp2, const float* __restrict__ b43,
                                               unsigned short* __restrict__ Wg, float* __restrict__ bgc) {
    __shared__ float u[256], red[256];
    int n = blockIdx.x, tid = threadIdx.x;
    u[tid] = Uf[n * 256 + tid];
    __syncthreads();
    float s = 0.f;
    #pragma unroll 16
    for (int o = 0; o < 256; o++) s += u[o] * wsp2[o * 256 + tid];
    Wg[n * 256 + tid] = f2bf(s);
    red[tid] = u[tid] * bsp2[tid];
    __syncthreads();
    for (int st = 128; st > 0; st >>= 1) {
        if (tid < st) red[tid] += red[tid + st];
        __syncthreads();
    }
    if (tid == 0) bgc[n] = b43[n] + red[0];
}

// ---------------------------------------------------------------- channels-first MFMA GEMM
// C[n][m] (or TSTORE: C[m][n]) = sum_k B[n][k] * A(k, m) + bias[n]
// AMODE 0: A[k][m]; 1: s2d gather; 2: x 2x2-patch gather (K=12 pad 32); 3: A[m][K];
// 7: F1T read; 8: I1T read; 9: amp=sqrt(re^2+im^2) from F2C on the fly
template<int AMODE, int SPLIT, int LRELU, int TSTORE, int ABF16, int CBF16>
__global__ __launch_bounds__(256) void k_mmcf(const void* __restrict__ Asrc_,
                                              const unsigned short* __restrict__ Bh,
                                              const unsigned short* __restrict__ Bl,
                                              const float* __restrict__ bias, void* __restrict__ C_,
                                              int M, int N, int K, int cshift, int wshift, int srcW,
                                              int gy) {
    const float* Af = (const float*)Asrc_;
    const unsigned short* A16 = (const unsigned short*)Asrc_;
    float* Cf = (float*)C_;
    unsigned short* C16 = (unsigned short*)C_;
    __shared__ unsigned short AhS[128 * 40];
    __shared__ unsigned short BhS[64 * 40];
    __shared__ unsigned short AlS[SPLIT ? 128 * 40 : 8];
    __shared__ unsigned short BlS[SPLIT ? 64 * 40 : 8];
    int tid = threadIdx.x;
    // bijective XCD-chunk remap (m204), y-inner work decomposition
    int nwg = (int)gridDim.x;
    int bid = blockIdx.x;
    int qq = nwg >> 3, rr = nwg & 7;
    int xcd = bid & 7, ixw = bid >> 3;
    int work = (xcd < rr) ? (xcd * (qq + 1) + ixw) : (rr * (qq + 1) + (xcd - rr) * qq + ixw);
    int bx = work / gy;
    int by = work - bx * gy;
    int m0 = bx * 128;
    int n0 = by * 64;
    int wave = tid >> 6, lane = tid & 63;
    int wm = (wave >> 1) * 64, wn = (wave & 1) * 32;
    int l15 = lane & 15, quad = lane >> 4;
    int lk = quad * 8, lk4 = quad * 4;
    fx4 acc[4][2];
    #pragma unroll
    for (int a = 0; a < 4; a++)
        #pragma unroll
        for (int b = 0; b < 2; b++)
            acc[a][b] = (fx4){0.f, 0.f, 0.f, 0.f};

    int mm = tid & 127;
    int kpb = tid >> 7;
    int gm = m0 + mm;
    int oj = 0, oi = 0, cA = 0, kfA = 0, tauA = 0;
    size_t abase = 0;
    if (AMODE == 1) { oj = gm & ((1 << wshift) - 1); oi = gm >> wshift; }
    if (AMODE == 2) { oj = gm & 255; oi = gm >> 8; }
    if (AMODE == 3) abase = (size_t)gm * K;
    if (AMODE == 7) { cA = gm / 65; kfA = gm - cA * 65; }
    if (AMODE == 8) { cA = gm >> 7; tauA = gm & 127; }
    if (AMODE == 9) { cA = gm / 65; kfA = gm - cA * 65; }   // cA = t, kfA = kf

    for (int kb = 0; kb < K; kb += 32) {
        if (AMODE == 3 && ABF16 && !SPLIT) {
            // contiguous-in-k source: direct 16B vector loads
            #pragma unroll
            for (int half = 0; half < 2; half++) {
                sh8 hv = *(const sh8*)(const void*)&A16[abase + kb + kpb * 16 + half * 8];
                *(sh8*)(void*)&AhS[mm * 40 + (kpb * 2 + half) * 8] = hv;
            }
        } else {
            #pragma unroll
            for (int half = 0; half < 2; half++) {
                sh8 hv, lv;
                #pragma unroll
                for (int tt = 0; tt < 4; tt++) {
                    int kp = kpb * 8 + half * 4 + tt;
                    int k0 = kb + kp * 2;
                    unsigned short h0, h1;
                    if (ABF16) {
                        size_t ad0, ad1;
                        if (AMODE == 0) {
                            ad0 = (size_t)k0 * M + gm;
                            ad1 = ad0 + M;
                        } else if (AMODE == 1) {
                            int c = k0 & ((1 << cshift) - 1);
                            int dydx = k0 >> cshift;
                            int dy = dydx >> 1, dx = dydx & 1;
                            size_t pix = (size_t)(2 * oi + dy) * srcW + (2 * oj + dx);
                            size_t plane = (size_t)srcW * srcW;
                            ad0 = (size_t)c * plane + pix;
                            ad1 = ad0 + plane;
                        } else if (AMODE == 3) {
                            ad0 = abase + k0;
                            ad1 = ad0 + 1;
                        } else if (AMODE == 7) {
                            int t0 = k0 & 127, hf = k0 >> 7;
                            ad0 = (size_t)(cA * 128 + t0) * 256 + hf * 128 + kfA;
                            ad1 = ad0 + 256;
                        } else {               // AMODE 8
                            int j0 = k0, j1 = k0 + 1;
                            int kf0 = (j0 < 65) ? j0 : ((j0 < 130) ? j0 - 65 : 0);
                            int hf0 = (j0 >= 65 && j0 < 130) ? 1 : 0;
                            int kf1 = (j1 < 65) ? j1 : ((j1 < 130) ? j1 - 65 : 0);
                            int hf1 = (j1 >= 65 && j1 < 130) ? 1 : 0;
                            ad0 = (size_t)(cA * 65 + kf0) * 256 + hf0 * 128 + tauA;
                            ad1 = (size_t)(cA * 65 + kf1) * 256 + hf1 * 128 + tauA;
                        }
                        h0 = A16[ad0];
                        h1 = A16[ad1];
                    } else {
                        float a0, a1;
                        if (AMODE == 2) {
                            if (k0 < 12) {
                                int d0 = k0 / 3, c0 = k0 - d0 * 3;
                                int k1 = k0 + 1;
                                int d1x = k1 / 3, c1 = k1 - d1x * 3;
                                a0 = Af[(size_t)c0 * NPIX + (size_t)(2 * oi + (d0 >> 1)) * 512 + 2 * oj + (d0 & 1)];
                                a1 = Af[(size_t)c1 * NPIX + (size_t)(2 * oi + (d1x >> 1)) * 512 + 2 * oj + (d1x & 1)];
                            } else { a0 = 0.f; a1 = 0.f; }
                        } else if (AMODE == 9) {
                            size_t ad = (size_t)cA * 16640 + (size_t)k0 * 65 + kfA;
                            float re0 = Af[ad], im0 = Af[ad + 2129920];
                            float re1 = Af[ad + 65], im1 = Af[ad + 65 + 2129920];
                            a0 = sqrtf(re0 * re0 + im0 * im0);
                            a1 = sqrtf(re1 * re1 + im1 * im1);
                        } else {               // AMODE 0 fp32
                            size_t ad0 = (size_t)k0 * M + gm;
                            a0 = Af[ad0];
                            a1 = Af[ad0 + M];
                        }
                        h0 = f2bf(a0);
                        h1 = f2bf(a1);
                        if (SPLIT) {
                            lv[tt * 2] = (short)f2bf(a0 - bf2f(h0));
                            lv[tt * 2 + 1] = (short)f2bf(a1 - bf2f(h1));
                        }
                    }
                    hv[tt * 2] = (short)h0;
                    hv[tt * 2 + 1] = (short)h1;
                }
                int coff = (kpb * 2 + half) * 8;
                *(sh8*)(void*)&AhS[mm * 40 + coff] = hv;
                if (SPLIT) *(sh8*)(void*)&AlS[mm * 40 + coff] = lv;
            }
        }
        {
            int n = tid >> 2, seg = tid & 3;
            size_t gb = (size_t)(n0 + n) * K + kb + seg * 8;
            *(sh8*)(void*)&BhS[n * 40 + seg * 8] = *(const sh8*)(const void*)&Bh[gb];
            if (SPLIT) *(sh8*)(void*)&BlS[n * 40 + seg * 8] = *(const sh8*)(const void*)&Bl[gb];
        }
        __syncthreads();
        sh8 af[4], bf[2], afl[4], bfl[2];
        #pragma unroll
        for (int mt = 0; mt < 4; mt++) {
            af[mt] = *(const sh8*)(const void*)&AhS[(wm + mt * 16 + l15) * 40 + lk];
            if (SPLIT) afl[mt] = *(const sh8*)(const void*)&AlS[(wm + mt * 16 + l15) * 40 + lk];
        }
        #pragma unroll
        for (int nt = 0; nt < 2; nt++) {
            bf[nt] = *(const sh8*)(const void*)&BhS[(wn + nt * 16 + l15) * 40 + lk];
            if (SPLIT) bfl[nt] = *(const sh8*)(const void*)&BlS[(wn + nt * 16 + l15) * 40 + lk];
        }
        #pragma unroll
        for (int mt = 0; mt < 4; mt++)
            #pragma unroll
            for (int nt = 0; nt < 2; nt++) {
                acc[mt][nt] = __builtin_amdgcn_mfma_f32_16x16x32_bf16(af[mt], bf[nt], acc[mt][nt], 0, 0, 0);
                if (SPLIT) {
                    acc[mt][nt] = __builtin_amdgcn_mfma_f32_16x16x32_bf16(af[mt], bfl[nt], acc[mt][nt], 0, 0, 0);
                    acc[mt][nt] = __builtin_amdgcn_mfma_f32_16x16x32_bf16(afl[mt], bf[nt], acc[mt][nt], 0, 0, 0);
                }
            }
        __syncthreads();
    }
    #pragma unroll
    for (int nt = 0; nt < 2; nt++) {
        int n = n0 + wn + nt * 16 + l15;
        float bs = bias[n];
        #pragma unroll
        for (int mt = 0; mt < 4; mt++) {
            int mbase = m0 + wm + mt * 16 + lk4;
            if (TSTORE) {
                #pragma unroll
                for (int r = 0; r < 4; r++) {
                    float q = acc[mt][nt][r] + bs;
                    if (LRELU) q = (q < 0.f) ? 0.1f * q : q;
                    if (CBF16) C16[(size_t)(mbase + r) * N + n] = f2bf(q);
                    else       Cf[(size_t)(mbase + r) * N + n] = q;
                }
            } else if (CBF16) {
                ush4 v;
                #pragma unroll
                for (int r = 0; r < 4; r++) {
                    float q = acc[mt][nt][r] + bs;
                    if (LRELU) q = (q < 0.f) ? 0.1f * q : q;
                    v[r] = f2bf(q);
                }
                *(ush4*)(void*)&C16[(size_t)n * M + mbase] = v;
            } else {
                float4 v;
                float* vp = (float*)&v;
                #pragma unroll
                for (int r = 0; r < 4; r++) {
                    float q = acc[mt][nt][r] + bs;
                    if (LRELU) q = (q < 0.f) ? 0.1f * q : q;
                    vp[r] = q;
                }
                *(float4*)&Cf[(size_t)n * M + mbase] = v;
            }
        }
    }
}

// ---------------------------------------------------------------- z = a*(cos a, sin a), flattened full-wave, bf16
__global__ __launch_bounds__(256) void k_zbuild(const float* __restrict__ A2, unsigned short* __restrict__ Z) {
    int idx = blockIdx.x * 256 + threadIdx.x;   // < 2129920
    int ct = idx / 65, kf = idx - ct * 65;
    int c = ct >> 7, t = ct & 127;
    float a = A2[idx];
    float s_, c_;
    sincosf(a, &s_, &c_);
    size_t m = (size_t)c * 65 + kf;
    Z[(size_t)t * 16640 + m] = f2bf(a * c_);
    Z[2129920 + (size_t)t * 16640 + m] = f2bf(a * s_);
}

// ---------------------------------------------------------------- h3s = W21c @ I2T + b21c  (3ch @128^2, K=256)
__global__ __launch_bounds__(64) void k_h3s(const float* __restrict__ I2T, const float* __restrict__ W21c,
                                            const float* __restrict__ b21c, float* __restrict__ h3s) {
    __shared__ float wa[768], bs[3];
    int tid = threadIdx.x;
    for (int i = tid; i < 768; i += 64) wa[i] = W21c[i];
    if (tid < 3) bs[tid] = b21c[tid];
    __syncthreads();
    int q = blockIdx.x * 64 + tid;
    float a0 = bs[0], a1 = bs[1], a2 = bs[2];
    #pragma unroll 4
    for (int c = 0; c < 256; c++) {
        float v = I2T[(size_t)c * 16384 + q];
        a0 += wa[c] * v;
        a1 += wa[256 + c] * v;
        a2 += wa[512 + c] * v;
    }
    h3s[q] = a0; h3s[16384 + q] = a1; h3s[32768 + q] = a2;
}

// ---------------------------------------------------------------- channels-first bilinear x2 resize
__global__ __launch_bounds__(256) void k_resize2(const float* __restrict__ src, float* __restrict__ dst,
                                                 int C, int H) {
    int W2 = 2 * H;
    size_t idx = (size_t)blockIdx.x * 256 + threadIdx.x;
    size_t plane = (size_t)W2 * W2;
    if (idx >= (size_t)C * plane) return;
    int c = (int)(idx / plane);
    int rem = (int)(idx - (size_t)c * plane);
    int i = rem / W2, j = rem - i * W2;
    int ky = i >> 1, ylo, yhi; float wyl, wyh;
    if ((i & 1) == 0) { ylo = ky - 1; yhi = ky; wyl = .25f; wyh = .75f; if (ylo < 0) { ylo = 0; wyl = 0.f; wyh = 1.f; } }
    else              { ylo = ky; yhi = ky + 1; wyl = .75f; wyh = .25f; if (yhi > H - 1) { yhi = H - 1; wyh = 0.f; wyl = 1.f; } }
    int kx = j >> 1, xlo, xhi; float wxl, wxh;
    if ((j & 1) == 0) { xlo = kx - 1; xhi = kx; wxl = .25f; wxh = .75f; if (xlo < 0) { xlo = 0; wxl = 0.f; wxh = 1.f; } }
    else              { xlo = kx; xhi = kx + 1; wxl = .75f; wxh = .25f; if (xhi > H - 1) { xhi = H - 1; wxh = 0.f; wxl = 1.f; } }
    const float* p = src + (size_t)c * H * H;
    dst[idx] = wyl * (wxl * p[(size_t)ylo * H + xlo] + wxh * p[(size_t)ylo * H + xhi]) +
               wyh * (wxl * p[(size_t)yhi * H + xlo] + wxh * p[(size_t)yhi * H + xhi]);
}

// ---------------------------------------------------------------- final fused stage @512^2
__global__ __launch_bounds__(256) void k_final(const float* __restrict__ x,
                                               const float* __restrict__ dark, const int* __restrict__ gmax,
                                               const float* __restrict__ wcf1, const float* __restrict__ bcf1,
                                               const float* __restrict__ Wc, const float* __restrict__ bc,
                                               const float* __restrict__ g4, const float* __restrict__ h3,
                                               float* __restrict__ out) {
    __shared__ float dimt[32], w1[192], b1[64], wb[192], bcs[3];
    int tid = threadIdx.x;
    if (tid < 32) dimt[tid] = powf(10000.f, (float)(2 * (tid >> 1)) / 32.f);
    if (tid < 192) w1[tid] = wcf1[tid];
    if (tid < 64) b1[tid] = bcf1[tid];
    if (tid < 192) { int r = tid / 64, c = tid - (tid / 64) * 64; wb[tid] = Wc[r * 128 + 64 + c]; }
    if (tid < 3) bcs[tid] = bc[tid];
    __syncthreads();
    int p = blockIdx.x * 256 + threadIdx.x;
    int i = p >> 9, j = p & 511;
    const float scale = 2.f * PI_F;
    float inv511 = scale / (511.f + 1e-6f);
    float xe = (float)j * inv511, ye = (float)i * inv511;
    float gm = __int_as_float(gmax[0]);
    float ze = dark[p] / (gm + 1e-6f) * scale;
    float x0 = x[p], x1 = x[p + NPIX], x2 = x[p + 2 * NPIX];

    int ky = i >> 1, ylo, yhi; float wyl, wyh;
    if ((i & 1) == 0) { ylo = ky - 1; yhi = ky; wyl = .25f; wyh = .75f; if (ylo < 0) { ylo = 0; wyl = 0.f; wyh = 1.f; } }
    else              { ylo = ky; yhi = ky + 1; wyl = .75f; wyh = .25f; if (yhi > 255) { yhi = 255; wyh = 0.f; wyl = 1.f; } }
    int kx = j >> 1, xlo, xhi; float wxl, wxh;
    if ((j & 1) == 0) { xlo = kx - 1; xhi = kx; wxl = .25f; wxh = .75f; if (xlo < 0) { xlo = 0; wxl = 0.f; wxh = 1.f; } }
    else              { xlo = kx; xhi = kx + 1; wxl = .75f; wxh = .25f; if (xhi > 255) { xhi = 255; wxh = 0.f; wxl = 1.f; } }
    int s00 = ylo * 256 + xlo, s01 = ylo * 256 + xhi, s10 = yhi * 256 + xlo, s11 = yhi * 256 + xhi;
    float w00 = wyl * wxl, w01 = wyl * wxh, w10 = wyh * wxl, w11 = wyh * wxh;

    float a0 = 0.f, a1 = 0.f, a2 = 0.f;
    #pragma unroll 1
    for (int c = 0; c < 64; c++) {
        float e = (c < 16) ? xe / dimt[c] : (c < 32) ? ye / dimt[c - 16] : ze / dimt[c - 32];
        float sn, cs;
        __sincosf(e, &sn, &cs);
        float pos = ((c & 1) == 0) ? sn : cs;
        float ape = pos + w1[c * 3] * x0 + w1[c * 3 + 1] * x1 + w1[c * 3 + 2] * x2 + b1[c];
        const float* gp = g4 + (size_t)c * 65536;
        float gv = w00 * gp[s00] + w01 * gp[s01] + w10 * gp[s10] + w11 * gp[s11];
        float s = gv * ape;
        a0 += wb[c] * s; a1 += wb[64 + c] * s; a2 += wb[128 + c] * s;
    }
    float f0 = w00 * h3[s00] + w01 * h3[s01] + w10 * h3[s10] + w11 * h3[s11];
    const float* h1 = h3 + 65536;
    float f1 = w00 * h1[s00] + w01 * h1[s01] + w10 * h1[s10] + w11 * h1[s11];
    const float* h2 = h3 + 131072;
    float f2 = w00 * h2[s00] + w01 * h2[s01] + w10 * h2[s10] + w11 * h2[s11];
    out[p]            = a0 + f0 + bcs[0] + x0;
    out[NPIX + p]     = a1 + f1 + bcs[1] + x1;
    out[2 * NPIX + p] = a2 + f2 + bcs[2] + x2;
}

// ================================================================ launcher
extern "C" void kernel_launch(void* const* d_in, const int* in_sizes, int n_in,
                              void* d_out, int out_size, void* d_ws, size_t ws_size,
                              hipStream_t stream) {
    const float* x      = (const float*)d_in[0];
    const float* w_cf1  = (const float*)d_in[1];  const float* b_cf1 = (const float*)d_in[2];
    const float* w_e1   = (const float*)d_in[3];  const float* b_e1  = (const float*)d_in[4];
    const float* w_e2   = (const float*)d_in[5];  const float* b_e2  = (const float*)d_in[6];
    const float* w_d1   = (const float*)d_in[7];  const float* b_d1  = (const float*)d_in[8];
    const float* w_d2   = (const float*)d_in[9];  const float* b_d2  = (const float*)d_in[10];
    // 11..14: pha branch is dead code in the reference
    const float* w_amp1 = (const float*)d_in[15]; const float* b_amp1 = (const float*)d_in[16];
    const float* w_amp2 = (const float*)d_in[17]; const float* b_amp2 = (const float*)d_in[18];
    const float* w_sp1  = (const float*)d_in[19]; const float* b_sp1  = (const float*)d_in[20];
    const float* w_sp2  = (const float*)d_in[21]; const float* b_sp2  = (const float*)d_in[22];
    const float* w_u1   = (const float*)d_in[23]; const float* b_u1   = (const float*)d_in[24];
    const float* w_u2   = (const float*)d_in[25]; const float* b_u2   = (const float*)d_in[26];
    const float* w_u3   = (const float*)d_in[27]; const float* b_u3   = (const float*)d_in[28];
    const float* w_u4   = (const float*)d_in[29]; const float* b_u4   = (const float*)d_in[30];
    const float* w_cf2  = (const float*)d_in[31]; const float* b_cf2  = (const float*)d_in[32];
    const float* w_cf3  = (const float*)d_in[33]; const float* b_cf3  = (const float*)d_in[34];
    float* out = (float*)d_out;

    char* ws = (char*)d_ws;
    constexpr size_t MiB = 1ull << 20;
    float*  dark   = (float*)(ws + 0 * MiB);
    float*  tmp    = (float*)(ws + 1 * MiB);
    int*    gmax   = (int*)  (ws + 2 * MiB);
    float*  Wc     = (float*)(ws + 2 * MiB + 1024);
    float*  bc     = (float*)(ws + 2 * MiB + 2560);
    float*  W21c   = (float*)(ws + 2 * MiB + 4096);
    float*  b21c   = (float*)(ws + 2 * MiB + 7168);
    float*  b43    = (float*)(ws + 2 * MiB + 7424);
    unsigned short* d1ch = (unsigned short*)(ws + 3 * MiB);       // bf16 [128][32]
    float*  b1c    = (float*)(ws + 3 * MiB + 16384);
    float*  Uf     = (float*)(ws + 3 * MiB + 32768);              // fp32 [64][256]
    unsigned short* Wg = (unsigned short*)(ws + 3 * MiB + 131072);// bf16 [64][256]
    float*  bgc    = (float*)(ws + 3 * MiB + 196608);
    unsigned short* xd1 = (unsigned short*)(ws + 67 * MiB);   // bf16 [128][65536] = 16 MiB
    unsigned short* xd2 = (unsigned short*)(ws + 99 * MiB);   // bf16 [256][16384] =  8 MiB
    unsigned short* F1T = (unsigned short*)(ws + 115 * MiB);  // bf16 [32768][256] = 16 MiB
    float*  F2C    = (float*)(ws + 147 * MiB);                // fp32 (feeds sqrt fused in amp1)
    float*  A1     = (float*)(ws + 173 * MiB);
    float*  A2     = (float*)(ws + 182 * MiB);
    unsigned short* Zbuf = (unsigned short*)(ws + 115 * MiB); // bf16 (F1T dead after F2)
    unsigned short* I1T  = (unsigned short*)(ws + 132 * MiB); // bf16 [16640][256] = 8.5 MiB
    float*  I2T    = (float*)(ws + 149 * MiB);                // fp32 (feeds h3s fp32 dot)
    float*  h3s    = (float*)(ws + 11 * MiB);
    float*  h3     = (float*)(ws + 27 * MiB);
    unsigned short* s1 = (unsigned short*)(ws + 31 * MiB);    // bf16 [256][16384] = 8 MiB
    float*  g4out  = (float*)(ws + 71 * MiB);
    float*  g4s    = (float*)(ws + 87 * MiB);
    unsigned short* wb16 = (unsigned short*)(ws + 192 * MiB);
    unsigned short* d2h = wb16 + 65536,   * d2l = wb16 + 196608;
    unsigned short* a1h = wb16 + 327680,  * a1l = wb16 + 393216;
    unsigned short* a2h = wb16 + 458752,  * a2l = wb16 + 524288;
    unsigned short* s1h = wb16 + 589824;
    unsigned short* BfH = wb16 + 786432,  * BfL = wb16 + 819200;
    unsigned short* BfcH = wb16 + 851968, * BfcL = wb16 + 917504;
    unsigned short* BicH = wb16 + 983040, * BicL = wb16 + 1048576;
    unsigned short* BirH = wb16 + 1114112,* BirL = wb16 + 1134592;
    float* zbias = (float*)(ws + 195 * MiB + 512 * 1024);

    // 1) dark channel + gmax ; merged prep ; Wg compose
    k_mrow<<<512, 256, 0, stream>>>(x, tmp, gmax);
    k_mincol_max<<<1024, 256, 0, stream>>>(tmp, dark, gmax);
    k_prep<<<2066, 256, 0, stream>>>(
        w_e1, b_e1, w_e2, b_e2, w_d1, b_d1, d1ch, b1c,
        w_d2, d2h, d2l, w_amp1, a1h, a1l, w_amp2, a2h, a2l,
        w_sp1, s1h,
        w_u3, w_u4, Uf, b_u3, b_u4, b43,
        BfH, BfL, BfcH, BfcL, BicH, BicL, BirH, BirL, zbias,
        w_cf2, b_cf2, w_cf3, b_cf3, w_u2, b_u2, w_u1, b_u1, Wc, bc, W21c, b21c);
    k_prep2<<<64, 256, 0, stream>>>(Uf, w_sp2, b_sp2, b43, Wg, bgc);

    // 2) composed d1 = (w_d1∘w_e2∘w_e1) on 2x2 x-patches, K=12→32 ; d2
    k_mmcf<2, 0, 0, 0, 0, 1><<<1024, 256, 0, stream>>>(x, d1ch, nullptr, b1c, xd1, 65536, 128, 32, 0, 0, 0, 2);
    k_mmcf<1, 0, 0, 0, 1, 1><<<512, 256, 0, stream>>>(xd1, d2h, nullptr, b_d2, xd2, 16384, 256, 512, 7, 7, 256, 4);

    // 3) FFT section (amp = sqrt fused into amp1 A-stage)
    k_mmcf<3, 0, 0, 1, 1, 1><<<1024, 256, 0, stream>>>(xd2, BfH, nullptr, zbias, F1T, 32768, 256, 128, 0, 0, 0, 4);
    k_mmcf<7, 0, 0, 0, 1, 0><<<520, 256, 0, stream>>>(F1T, BfcH, nullptr, zbias, F2C, 16640, 256, 256, 0, 0, 0, 4);
    k_mmcf<9, 1, 1, 0, 0, 0><<<260, 256, 0, stream>>>(F2C, a1h, a1l, b_amp1, A1, 8320, 256, 256, 0, 0, 0, 4);
    k_mmcf<0, 1, 0, 0, 0, 0><<<260, 256, 0, stream>>>(A1, a2h, a2l, b_amp2, A2, 8320, 256, 256, 0, 0, 0, 4);
    k_zbuild<<<8320, 256, 0, stream>>>(A2, Zbuf);
    k_mmcf<0, 0, 0, 1, 1, 1><<<520, 256, 0, stream>>>(Zbuf, BicH, nullptr, zbias, I1T, 16640, 256, 256, 0, 0, 0, 4);
    k_mmcf<8, 0, 0, 1, 1, 0><<<512, 256, 0, stream>>>(I1T, BirH, nullptr, zbias, I2T, 32768, 128, 160, 0, 0, 0, 2);

    // 4) four path: h3s = W21c @ I2T ; resize 3ch
    k_h3s<<<256, 64, 0, stream>>>(I2T, W21c, b21c, h3s);
    k_resize2<<<768, 256, 0, stream>>>(h3s, h3, 3, 128);

    // 5) spat path: sp1 ; composed (u4·u3·sp2) GEMM ; resize 64ch
    k_mmcf<0, 0, 1, 0, 1, 1><<<512, 256, 0, stream>>>(xd2, s1h, nullptr, b_sp1, s1, 16384, 256, 256, 0, 0, 0, 4);
    k_mmcf<0, 0, 0, 0, 1, 0><<<128, 256, 0, stream>>>(s1, Wg, nullptr, bgc, g4s, 16384, 64, 256, 0, 0, 0, 1);
    k_resize2<<<16384, 256, 0, stream>>>(g4s, g4out, 64, 128);

    // 6) final fused stage
    k_final<<<1024, 256, 0, stream>>>(x, dark, gmax, w_cf1, b_cf1, Wc, bc, g4out, h3, out);
}